// Round 6
// baseline (1400.065 us; speedup 1.0000x reference)
//
#include <hip/hip_runtime.h>
#include <hip/hip_bf16.h>

#define N_NODES 200000
#define N_EDGES 800000
#define N_GRAPHS 512

typedef __attribute__((ext_vector_type(8))) short short8v;
typedef __attribute__((ext_vector_type(4))) float f32x4;
typedef __attribute__((ext_vector_type(2))) float f32x2;
typedef __attribute__((ext_vector_type(2))) unsigned int u32x2;
typedef __attribute__((ext_vector_type(4))) unsigned int u32x4;

__device__ inline float bf2f(unsigned int u) {
    union { unsigned int i; float f; } c;
    c.i = u << 16;
    return c.f;
}
__device__ inline unsigned short f2bf(float f) {
    union { __hip_bfloat16 h; unsigned short u; } c;
    c.h = __float2bfloat16(f);
    return c.u;
}

// ---------------- CSR build ----------------

__global__ __launch_bounds__(256) void count_edges(const int* __restrict__ dst, int E,
                                                   int* __restrict__ cnt) {
    int e = blockIdx.x * 256 + threadIdx.x;
    if (e < E) atomicAdd(&cnt[dst[e]], 1);
}

__global__ __launch_bounds__(512) void block_reduce(const int* __restrict__ in, int n,
                                                    int* __restrict__ bsum) {
    __shared__ int s[512];
    int i = blockIdx.x * 512 + threadIdx.x;
    s[threadIdx.x] = (i < n) ? in[i] : 0;
    __syncthreads();
    for (int off = 256; off; off >>= 1) {
        if (threadIdx.x < off) s[threadIdx.x] += s[threadIdx.x + off];
        __syncthreads();
    }
    if (threadIdx.x == 0) bsum[blockIdx.x] = s[0];
}

__global__ __launch_bounds__(512) void scan_bsums(int* bsum, int nb) {
    __shared__ int buf[2][512];
    int t = threadIdx.x;
    int v = (t < nb) ? bsum[t] : 0;
    buf[0][t] = v;
    __syncthreads();
    int src = 0;
    for (int off = 1; off < 512; off <<= 1) {
        int x = buf[src][t];
        if (t >= off) x += buf[src][t - off];
        buf[src ^ 1][t] = x;
        src ^= 1;
        __syncthreads();
    }
    if (t < nb) bsum[t] = buf[src][t] - v;  // exclusive
}

__global__ __launch_bounds__(512) void block_scan_write(const int* __restrict__ cnt,
                                                        const int* __restrict__ bsum, int n,
                                                        int* __restrict__ rowptr) {
    __shared__ int buf[2][512];
    int t = threadIdx.x;
    int i = blockIdx.x * 512 + t;
    int v = (i < n) ? cnt[i] : 0;
    buf[0][t] = v;
    __syncthreads();
    int src = 0;
    for (int off = 1; off < 512; off <<= 1) {
        int x = buf[src][t];
        if (t >= off) x += buf[src][t - off];
        buf[src ^ 1][t] = x;
        src ^= 1;
        __syncthreads();
    }
    int incl = buf[src][t];
    int base = bsum[blockIdx.x];
    if (i < n) rowptr[i] = base + incl - v;
    if (i == n - 1) rowptr[n] = base + incl;
}

__global__ __launch_bounds__(256) void fill_csr(const int* __restrict__ src,
                                                const int* __restrict__ dst, int E,
                                                const int* __restrict__ rowptr,
                                                int* __restrict__ cur, int* __restrict__ col) {
    int e = blockIdx.x * 256 + threadIdx.x;
    if (e < E) {
        int d = dst[e];
        int p = atomicAdd(&cur[d], 1);
        col[rowptr[d] + p] = src[e];
    }
}

__global__ __launch_bounds__(256) void compute_dinv(const int* __restrict__ rowptr, int n,
                                                    float* __restrict__ dinv) {
    int v = blockIdx.x * 256 + threadIdx.x;
    if (v < n) {
        int deg = rowptr[v + 1] - rowptr[v] + 1;  // +1 self loop
        dinv[v] = rsqrtf((float)deg);
    }
}

__global__ __launch_bounds__(64) void graph_bounds(const int* __restrict__ batch, int n, int ng,
                                                   int* __restrict__ gstart) {
    int b = blockIdx.x * 64 + threadIdx.x;
    if (b > ng) return;
    if (b == ng) { gstart[ng] = n; return; }
    int lo = 0, hi = n;
    while (lo < hi) {
        int mid = (lo + hi) >> 1;
        if (batch[mid] < b) lo = mid + 1; else hi = mid;
    }
    gstart[b] = lo;
}

// ---- xs[v] = x[v]*dinv[v] -> bf16 [N][80] (cols 78,79 = 0) ----

__global__ __launch_bounds__(256) void scale_x(const float* __restrict__ x,
                                               const float* __restrict__ dinv,
                                               unsigned short* __restrict__ XS) {
    int idx = blockIdx.x * 256 + threadIdx.x;
    int v = idx / 40, c = idx % 40;
    if (v >= N_NODES) return;
    if (c == 39) {
        *(unsigned int*)(XS + (size_t)v * 80 + 78) = 0u;
        return;
    }
    float dv = dinv[v];
    f32x2 xv = *(const f32x2*)(x + (size_t)v * 78 + c * 2);
    unsigned int pack = ((unsigned int)f2bf(xv.y * dv) << 16) | f2bf(xv.x * dv);
    *(unsigned int*)(XS + (size_t)v * 80 + c * 2) = pack;
}

// ---- aggregation on pre-scaled features: out[v] = dinv[v]*(sum_{u in N(v)} X[u] + X[v]) ----

template <int LD, int NCH, int NPB>
__global__ __launch_bounds__(256) void agg_sum(const unsigned short* __restrict__ X,
                                               const float* __restrict__ dinv,
                                               const int* __restrict__ rowptr,
                                               const int* __restrict__ col,
                                               unsigned short* __restrict__ out) {
    int tid = threadIdx.x;
    if (tid >= NPB * NCH) return;
    int v = blockIdx.x * NPB + tid / NCH;
    int c = tid % NCH;
    if (v >= N_NODES) return;
    u32x4 xv = *(const u32x4*)(X + (size_t)v * LD + c * 8);
    float a0 = bf2f(xv.x & 0xffffu), a1 = bf2f(xv.x >> 16);
    float a2 = bf2f(xv.y & 0xffffu), a3 = bf2f(xv.y >> 16);
    float a4 = bf2f(xv.z & 0xffffu), a5 = bf2f(xv.z >> 16);
    float a6 = bf2f(xv.w & 0xffffu), a7 = bf2f(xv.w >> 16);
    int r0 = rowptr[v], r1 = rowptr[v + 1];
    for (int e = r0; e < r1; ++e) {
        int u = col[e];
        u32x4 xu = *(const u32x4*)(X + (size_t)u * LD + c * 8);
        a0 += bf2f(xu.x & 0xffffu);
        a1 += bf2f(xu.x >> 16);
        a2 += bf2f(xu.y & 0xffffu);
        a3 += bf2f(xu.y >> 16);
        a4 += bf2f(xu.z & 0xffffu);
        a5 += bf2f(xu.z >> 16);
        a6 += bf2f(xu.w & 0xffffu);
        a7 += bf2f(xu.w >> 16);
    }
    float dv = dinv[v];
    u32x4 o;
    o.x = ((unsigned int)f2bf(a1 * dv) << 16) | f2bf(a0 * dv);
    o.y = ((unsigned int)f2bf(a3 * dv) << 16) | f2bf(a2 * dv);
    o.z = ((unsigned int)f2bf(a5 * dv) << 16) | f2bf(a4 * dv);
    o.w = ((unsigned int)f2bf(a7 * dv) << 16) | f2bf(a6 * dv);
    *(u32x4*)(out + (size_t)v * LD + c * 8) = o;
}

// ------- MFMA node GEMM: Cout = relu(A @ W + bias) * dinv[row], bf16 in/out -------

template <int KREAL, int NREAL, int LDA, int LDC, int NF, int KS>
__global__ __launch_bounds__(256) void gemm_mfma_node(const unsigned short* __restrict__ A,
                                                      const float* __restrict__ W,
                                                      const float* __restrict__ bias,
                                                      const float* __restrict__ dinv,
                                                      unsigned short* __restrict__ Cout, int M) {
    __shared__ unsigned short Bs[NF * KS * 64 * 8];
    int tid = threadIdx.x;
    for (int idx = tid; idx < NF * KS * 64; idx += 256) {
        int l = idx & 63, ks = (idx >> 6) % KS, nf = idx / (64 * KS);
        int k0 = ks * 32 + 8 * (l >> 4);
        int cc = nf * 16 + (l & 15);
        short8v t;
#pragma unroll
        for (int j = 0; j < 8; j++) {
            int k = k0 + j;
            float w = (k < KREAL && cc < NREAL) ? W[(size_t)k * NREAL + cc] : 0.f;
            t[j] = (short)f2bf(w);
        }
        *(short8v*)&Bs[idx * 8] = t;
    }
    __syncthreads();

    int lane = tid & 63, wid = tid >> 6;
    int m0 = blockIdx.x * 128 + wid * 32;
    float biasr[NF];
#pragma unroll
    for (int nf = 0; nf < NF; nf++) {
        int cc = nf * 16 + (lane & 15);
        biasr[nf] = (cc < NREAL) ? bias[cc] : 0.f;
    }
    f32x4 acc[2][NF];
#pragma unroll
    for (int mf = 0; mf < 2; mf++)
#pragma unroll
        for (int nf = 0; nf < NF; nf++) acc[mf][nf] = (f32x4){0.f, 0.f, 0.f, 0.f};

    int ra = min(m0 + (lane & 15), M - 1);
    int rb = min(m0 + 16 + (lane & 15), M - 1);
#pragma unroll
    for (int ks = 0; ks < KS; ks++) {
        int koff = ks * 32 + 8 * (lane >> 4);
        short8v a0 = *(const short8v*)(A + (size_t)ra * LDA + koff);
        short8v a1 = *(const short8v*)(A + (size_t)rb * LDA + koff);
#pragma unroll
        for (int nf = 0; nf < NF; nf++) {
            short8v b = *(const short8v*)&Bs[((nf * KS + ks) * 64 + lane) * 8];
            acc[0][nf] = __builtin_amdgcn_mfma_f32_16x16x32_bf16(a0, b, acc[0][nf], 0, 0, 0);
            acc[1][nf] = __builtin_amdgcn_mfma_f32_16x16x32_bf16(a1, b, acc[1][nf], 0, 0, 0);
        }
    }
    float dr[2][4];
#pragma unroll
    for (int mf = 0; mf < 2; mf++)
#pragma unroll
        for (int r = 0; r < 4; r++) {
            int row = m0 + mf * 16 + 4 * (lane >> 4) + r;
            dr[mf][r] = dinv[min(row, M - 1)];
        }
#pragma unroll
    for (int mf = 0; mf < 2; mf++) {
#pragma unroll
        for (int nf = 0; nf < NF; nf++) {
            int cc = nf * 16 + (lane & 15);
#pragma unroll
            for (int r = 0; r < 4; r++) {
                int row = m0 + mf * 16 + 4 * (lane >> 4) + r;
                float v = fmaxf(acc[mf][nf][r] + biasr[nf], 0.f) * dr[mf][r];
                unsigned short o = (cc < NREAL) ? f2bf(v) : (unsigned short)0;
                if (row < M) Cout[(size_t)row * LDC + cc] = o;
            }
        }
    }
}

// ------- layer-3 GEMM fused with per-graph segment-max; grid (5 col-blocks, 512 graphs) ----

__global__ __launch_bounds__(256) void seg_gemm_max(const unsigned short* __restrict__ A,
                                                    const float* __restrict__ W3,
                                                    const float* __restrict__ b3,
                                                    const int* __restrict__ gstart,
                                                    float* __restrict__ g3) {
    __shared__ unsigned short Bs[4 * 5 * 64 * 8];  // 20 KB
    __shared__ float wmax[4][64];
    int g = blockIdx.y;
    int c0 = blockIdx.x * 64;
    int r0 = gstart[g], r1 = gstart[g + 1];
    int tid = threadIdx.x, lane = tid & 63, wid = tid >> 6;

    for (int idx = tid; idx < 1280; idx += 256) {
        int l = idx & 63, ks = (idx >> 6) % 5, nf = idx / 320;
        int k0 = ks * 32 + 8 * (l >> 4);
        int cc = c0 + nf * 16 + (l & 15);
        short8v t;
#pragma unroll
        for (int j = 0; j < 8; j++) {
            int k = k0 + j;
            float w = (k < 156 && cc < 312) ? W3[(size_t)k * 312 + cc] : 0.f;
            t[j] = (short)f2bf(w);
        }
        *(short8v*)&Bs[idx * 8] = t;
    }
    __syncthreads();

    float biasr[4], cmax[4];
#pragma unroll
    for (int nf = 0; nf < 4; nf++) {
        int cc = c0 + nf * 16 + (lane & 15);
        biasr[nf] = (cc < 312) ? b3[cc] : 0.f;
        cmax[nf] = 0.f;
    }

    for (int mt = r0 + wid * 32; mt < r1; mt += 128) {
        f32x4 acc[2][4];
#pragma unroll
        for (int mf = 0; mf < 2; mf++)
#pragma unroll
            for (int nf = 0; nf < 4; nf++) acc[mf][nf] = (f32x4){0.f, 0.f, 0.f, 0.f};
        int ra = min(mt + (lane & 15), N_NODES - 1);
        int rb = min(mt + 16 + (lane & 15), N_NODES - 1);
#pragma unroll
        for (int ks = 0; ks < 5; ks++) {
            int koff = ks * 32 + 8 * (lane >> 4);
            short8v a0 = *(const short8v*)(A + (size_t)ra * 160 + koff);
            short8v a1 = *(const short8v*)(A + (size_t)rb * 160 + koff);
#pragma unroll
            for (int nf = 0; nf < 4; nf++) {
                short8v b = *(const short8v*)&Bs[((nf * 5 + ks) * 64 + lane) * 8];
                acc[0][nf] = __builtin_amdgcn_mfma_f32_16x16x32_bf16(a0, b, acc[0][nf], 0, 0, 0);
                acc[1][nf] = __builtin_amdgcn_mfma_f32_16x16x32_bf16(a1, b, acc[1][nf], 0, 0, 0);
            }
        }
#pragma unroll
        for (int mf = 0; mf < 2; mf++) {
#pragma unroll
            for (int nf = 0; nf < 4; nf++) {
#pragma unroll
                for (int r = 0; r < 4; r++) {
                    int row = mt + mf * 16 + 4 * (lane >> 4) + r;
                    float v = fmaxf(acc[mf][nf][r] + biasr[nf], 0.f);
                    if (row < r1) cmax[nf] = fmaxf(cmax[nf], v);
                }
            }
        }
    }
#pragma unroll
    for (int nf = 0; nf < 4; nf++) {
        float m = cmax[nf];
        m = fmaxf(m, __shfl_xor(m, 16));
        m = fmaxf(m, __shfl_xor(m, 32));
        if (lane < 16) wmax[wid][nf * 16 + lane] = m;
    }
    __syncthreads();
    if (tid < 64) {
        float m = fmaxf(fmaxf(wmax[0][tid], wmax[1][tid]), fmaxf(wmax[2][tid], wmax[3][tid]));
        int cc = c0 + tid;
        if (cc < 312) g3[(size_t)g * 312 + cc] = m;
    }
}

// ---------------- head GEMMs: split-K, atomicAdd into bias-initialized C ----------------

__global__ __launch_bounds__(256) void init_bias_all(float* __restrict__ gg,
                                                     const float* __restrict__ bg1,
                                                     float* __restrict__ xc,
                                                     const float* __restrict__ bg2,
                                                     const float* __restrict__ bxt,
                                                     float* __restrict__ f1,
                                                     const float* __restrict__ bf1,
                                                     float* __restrict__ f2,
                                                     const float* __restrict__ bf2) {
    int idx = blockIdx.x * 256 + threadIdx.x;
    int row = idx / 2816, c = idx % 2816;
    if (row >= N_GRAPHS) return;
    if (c < 1024) gg[(size_t)row * 1024 + c] = bg1[c];
    else if (c < 1280) {
        int j = c - 1024;
        xc[(size_t)row * 256 + j] = (j < 128) ? bg2[j] : bxt[j - 128];
    } else if (c < 2304)
        f1[(size_t)row * 1024 + (c - 1280)] = bf1[c - 1280];
    else
        f2[(size_t)row * 512 + (c - 2304)] = bf2[c - 2304];
}

template <int RELUA>
__global__ __launch_bounds__(256) void gemm_splitk(const float* __restrict__ A,
                                                   const float* __restrict__ B,
                                                   float* __restrict__ C, int M, int N, int K,
                                                   int ldc, int Kc) {
    __shared__ float As[16][17];
    __shared__ float Bs[16][64];
    int bx = blockIdx.x, by = blockIdx.y, bz = blockIdx.z;
    int tid = threadIdx.x;
    int lane = tid & 63, wy = tid >> 6;
    int n0 = bx * 64, m0 = by * 16;
    int k0 = bz * Kc, k1 = min(K, k0 + Kc);
    float acc[4] = {0.f, 0.f, 0.f, 0.f};
    for (int kt = k0; kt < k1; kt += 16) {
        {
            int r = tid >> 4, kk = tid & 15;
            int gm = m0 + r, gk = kt + kk;
            float v = (gk < k1 && gm < M) ? A[(size_t)gm * K + gk] : 0.f;
            if (RELUA) v = fmaxf(v, 0.f);
            As[kk][r] = v;
        }
#pragma unroll
        for (int l = 0; l < 4; l++) {
            int kk = wy + l * 4;
            int gk = kt + kk, gn = n0 + lane;
            Bs[kk][lane] = (gk < k1 && gn < N) ? B[(size_t)gk * N + gn] : 0.f;
        }
        __syncthreads();
#pragma unroll
        for (int kk = 0; kk < 16; kk++) {
            float b = Bs[kk][lane];
#pragma unroll
            for (int r = 0; r < 4; r++) acc[r] += As[kk][wy * 4 + r] * b;
        }
        __syncthreads();
    }
    int gn = n0 + lane;
    if (gn < N) {
#pragma unroll
        for (int r = 0; r < 4; r++) {
            int gm = m0 + wy * 4 + r;
            if (gm < M) atomicAdd(&C[(size_t)gm * ldc + gn], acc[r]);
        }
    }
}

// ---------------- conv head (rewritten): grid (2 o-halves, 512 graphs) ----------------
// Phase 1: A[t][o_l*8+k] = sum_{i: tg[i]=t} convw[o,i,k] via LDS ds_add (no RMW chain),
//          i-range split across 4 waves. Phase 2: c[n,o,w] = convb[o] +
//          sum_t sum_k emb[t][w+k]*A[t][o_l*8+k], vector LDS reads, 4 w per thread.

__global__ __launch_bounds__(256) void conv_head(const int* __restrict__ target,
                                                 const float* __restrict__ emb,
                                                 const float* __restrict__ convw,
                                                 const float* __restrict__ convb,
                                                 float* __restrict__ c) {
    __shared__ float A[26 * 128];
    __shared__ float emb_s[26 * 128 + 16];  // +pad: phase-2 reads up to 11 past row end
    __shared__ int tg[1000];
    int n = blockIdx.y, oh = blockIdx.x;
    int tid = threadIdx.x, lane = tid & 63, wid = tid >> 6;
    for (int i = tid; i < 26 * 128; i += 256) {
        A[i] = 0.f;
        emb_s[i] = emb[i];
    }
    if (tid < 16) emb_s[26 * 128 + tid] = 0.f;
    for (int i = tid; i < 1000; i += 256) tg[i] = target[n * 1000 + i];
    __syncthreads();

    // phase 1: lane owns (o_l = lane>>2, k2 = (lane&3)*2) -> 2 consecutive k
    {
        int o_l = lane >> 2, k2 = (lane & 3) * 2;
        const float* cw = convw + (size_t)(oh * 16 + o_l) * 8000 + k2;
        float* ap = &A[o_l * 8 + k2];
        int i0 = wid * 250, i1 = i0 + 250;
        for (int i = i0; i < i1; ++i) {
            int t = tg[i];
            f32x2 v = *(const f32x2*)(cw + i * 8);
            atomicAdd(&ap[t * 128 + 0], v.x);
            atomicAdd(&ap[t * 128 + 1], v.y);
        }
    }
    __syncthreads();

    // phase 2: group g = (o_l, w4): 16 x 31 groups of 4 w's
    for (int g = tid; g < 16 * 31; g += 256) {
        int o_l = g / 31, w4 = (g % 31) * 4;
        int o = oh * 16 + o_l;
        float b = convb[o];
        float acc0 = b, acc1 = b, acc2 = b, acc3 = b;
#pragma unroll 2
        for (int t = 0; t < 26; t++) {
            const float* ar = &A[t * 128 + o_l * 8];
            f32x4 a0 = *(const f32x4*)ar;
            f32x4 a1 = *(const f32x4*)(ar + 4);
            const float* er = &emb_s[t * 128 + w4];
            f32x4 e0 = *(const f32x4*)er;
            f32x4 e1 = *(const f32x4*)(er + 4);
            f32x4 e2 = *(const f32x4*)(er + 8);
            float e[12] = {e0.x, e0.y, e0.z, e0.w, e1.x, e1.y, e1.z, e1.w,
                           e2.x, e2.y, e2.z, e2.w};
            float a[8] = {a0.x, a0.y, a0.z, a0.w, a1.x, a1.y, a1.z, a1.w};
#pragma unroll
            for (int kk = 0; kk < 8; kk++) {
                acc0 += e[kk] * a[kk];
                acc1 += e[kk + 1] * a[kk];
                acc2 += e[kk + 2] * a[kk];
                acc3 += e[kk + 3] * a[kk];
            }
        }
        size_t base = (size_t)n * 3872 + o * 121 + w4;
        c[base] = acc0;
        if (w4 + 1 < 121) c[base + 1] = acc1;
        if (w4 + 2 < 121) c[base + 2] = acc2;
        if (w4 + 3 < 121) c[base + 3] = acc3;
    }
}

// ---------------- final N=1 matvec (relu on load) ----------------

__global__ __launch_bounds__(256) void rowdot(const float* __restrict__ f2,
                                              const float* __restrict__ Wo,
                                              const float* __restrict__ bo,
                                              float* __restrict__ out, int M, int K) {
    int row = blockIdx.x * 4 + (threadIdx.x >> 6);
    int lane = threadIdx.x & 63;
    if (row >= M) return;
    float acc = 0.f;
    for (int k = lane; k < K; k += 64) acc += fmaxf(f2[(size_t)row * K + k], 0.f) * Wo[k];
    for (int off = 32; off; off >>= 1) acc += __shfl_down(acc, off);
    if (lane == 0) out[row] = acc + bo[0];
}

// ---------------- launch ----------------

extern "C" void kernel_launch(void* const* d_in, const int* in_sizes, int n_in, void* d_out,
                              int out_size, void* d_ws, size_t ws_size, hipStream_t stream) {
    const float* x = (const float*)d_in[0];
    const int* ei = (const int*)d_in[1];
    const int* batch = (const int*)d_in[2];
    const int* target = (const int*)d_in[3];
    const float* W1 = (const float*)d_in[4];
    const float* b1 = (const float*)d_in[5];
    const float* W2 = (const float*)d_in[6];
    const float* b2 = (const float*)d_in[7];
    const float* W3 = (const float*)d_in[8];
    const float* b3 = (const float*)d_in[9];
    const float* Wg1 = (const float*)d_in[10];
    const float* bg1 = (const float*)d_in[11];
    const float* Wg2 = (const float*)d_in[12];
    const float* bg2 = (const float*)d_in[13];
    const float* emb = (const float*)d_in[14];
    const float* convw = (const float*)d_in[15];
    const float* convb = (const float*)d_in[16];
    const float* Wxt = (const float*)d_in[17];
    const float* bxt = (const float*)d_in[18];
    const float* Wf1 = (const float*)d_in[19];
    const float* bf1 = (const float*)d_in[20];
    const float* Wf2 = (const float*)d_in[21];
    const float* bf2 = (const float*)d_in[22];
    const float* Wo = (const float*)d_in[23];
    const float* bo = (const float*)d_in[24];
    float* out = (float*)d_out;

    const int N = N_NODES, E = N_EDGES;
    const int NB = (N + 511) / 512;

    char* ws = (char*)d_ws;
    size_t off = 0;
    auto alloc = [&](size_t bytes) -> char* {
        char* p = ws + off;
        off = (off + bytes + 255) & ~(size_t)255;
        return p;
    };
    int* cnt = (int*)alloc((size_t)N * 2 * 4);  // cnt + cur, one memset
    int* cur = cnt + N;
    int* rowptr = (int*)alloc((size_t)(N + 1) * 4);
    int* bsum = (int*)alloc(512 * 4);
    int* col = (int*)alloc((size_t)E * 4);
    float* dinv = (float*)alloc((size_t)N * 4);
    int* gstart = (int*)alloc((N_GRAPHS + 1) * 4);
    float* g3 = (float*)alloc((size_t)N_GRAPHS * 312 * 4);
    float* gg = (float*)alloc((size_t)N_GRAPHS * 1024 * 4);
    float* cbuf = (float*)alloc((size_t)N_GRAPHS * 3872 * 4);
    float* xc = (float*)alloc((size_t)N_GRAPHS * 256 * 4);
    float* f1 = (float*)alloc((size_t)N_GRAPHS * 1024 * 4);
    float* f2 = (float*)alloc((size_t)N_GRAPHS * 512 * 4);
    unsigned short* U = (unsigned short*)alloc((size_t)N * 160 * 2 + 512);
    unsigned short* P160 = (unsigned short*)alloc((size_t)N * 160 * 2 + 512);
    unsigned short* H1 = U + (size_t)N * 80;  // [N,80] second half of U

    const int* srcp = ei;
    const int* dstp = ei + E;

    // CSR + norm
    hipMemsetAsync(cnt, 0, (size_t)N * 2 * 4, stream);
    count_edges<<<(E + 255) / 256, 256, 0, stream>>>(dstp, E, cnt);
    block_reduce<<<NB, 512, 0, stream>>>(cnt, N, bsum);
    scan_bsums<<<1, 512, 0, stream>>>(bsum, NB);
    block_scan_write<<<NB, 512, 0, stream>>>(cnt, bsum, N, rowptr);
    fill_csr<<<(E + 255) / 256, 256, 0, stream>>>(srcp, dstp, E, rowptr, cur, col);
    compute_dinv<<<(N + 255) / 256, 256, 0, stream>>>(rowptr, N, dinv);
    graph_bounds<<<(N_GRAPHS + 1 + 63) / 64, 64, 0, stream>>>(batch, N, N_GRAPHS, gstart);

    // bias-init split-K outputs (one kernel)
    init_bias_all<<<(N_GRAPHS * 2816 + 255) / 256, 256, 0, stream>>>(gg, bg1, xc, bg2, bxt, f1,
                                                                     bf1, f2, bf2);

    const int MB = (N + 127) / 128;  // 1563

    // layer 1: XS = x*dinv (P160); A1 = aggsum(XS) (U80); h1' = relu(A1@W1+b1)*dinv (H1)
    scale_x<<<(N * 40 + 255) / 256, 256, 0, stream>>>(x, dinv, P160);
    agg_sum<80, 10, 25><<<(N + 24) / 25, 256, 0, stream>>>(P160, dinv, rowptr, col, U);
    gemm_mfma_node<78, 78, 80, 80, 5, 3><<<MB, 256, 0, stream>>>(U, W1, b1, dinv, H1, N);
    // layer 2: A2 = aggsum(h1') (P160[:,:80]); h2' = relu(A2@W2+b2)*dinv (U as [N,160])
    agg_sum<80, 10, 25><<<(N + 24) / 25, 256, 0, stream>>>(H1, dinv, rowptr, col, P160);
    gemm_mfma_node<78, 156, 80, 160, 10, 3><<<MB, 256, 0, stream>>>(P160, W2, b2, dinv, U, N);
    // layer 3: A3 = aggsum(h2') (P160 [N,160]); fused GEMM + per-graph segment max
    agg_sum<160, 20, 12><<<(N + 11) / 12, 256, 0, stream>>>(U, dinv, rowptr, col, P160);
    seg_gemm_max<<<dim3(5, N_GRAPHS), 256, 0, stream>>>(P160, W3, b3, gstart, g3);

    // graph head
    gemm_splitk<0><<<dim3(16, 32, 2), 256, 0, stream>>>(g3, Wg1, gg, 512, 1024, 312, 1024, 160);
    gemm_splitk<1><<<dim3(2, 32, 8), 256, 0, stream>>>(gg, Wg2, xc, 512, 128, 1024, 256, 128);

    // conv head
    conv_head<<<dim3(2, N_GRAPHS), 256, 0, stream>>>(target, emb, convw, convb, cbuf);
    gemm_splitk<0><<<dim3(2, 32, 16), 256, 0, stream>>>(cbuf, Wxt, xc + 128, 512, 128, 3872, 256, 256);

    // final MLP
    gemm_splitk<0><<<dim3(16, 32, 2), 256, 0, stream>>>(xc, Wf1, f1, 512, 1024, 256, 1024, 128);
    gemm_splitk<1><<<dim3(8, 32, 8), 256, 0, stream>>>(f1, Wf2, f2, 512, 512, 1024, 512, 128);
    rowdot<<<(N_GRAPHS + 3) / 4, 256, 0, stream>>>(f2, Wo, bo, out, N_GRAPHS, 512);
}

// Round 7
// 762.521 us; speedup vs baseline: 1.8361x; 1.8361x over previous
//
#include <hip/hip_runtime.h>
#include <hip/hip_bf16.h>

#define N_NODES 200000
#define N_EDGES 800000
#define N_GRAPHS 512

typedef __attribute__((ext_vector_type(8))) short short8v;
typedef __attribute__((ext_vector_type(4))) float f32x4;
typedef __attribute__((ext_vector_type(2))) float f32x2;
typedef __attribute__((ext_vector_type(2))) unsigned int u32x2;
typedef __attribute__((ext_vector_type(4))) unsigned int u32x4;
typedef __attribute__((ext_vector_type(4))) int i32x4;

__device__ inline float bf2f(unsigned int u) {
    union { unsigned int i; float f; } c;
    c.i = u << 16;
    return c.f;
}
__device__ inline unsigned short f2bf(float f) {
    union { __hip_bfloat16 h; unsigned short u; } c;
    c.h = __float2bfloat16(f);
    return c.u;
}

// ---------------- CSR build ----------------

__global__ __launch_bounds__(256) void count_edges(const int* __restrict__ dst, int E,
                                                   int* __restrict__ cnt) {
    int e = blockIdx.x * 256 + threadIdx.x;
    if (e < E) atomicAdd(&cnt[dst[e]], 1);
}

__global__ __launch_bounds__(512) void block_reduce(const int* __restrict__ in, int n,
                                                    int* __restrict__ bsum) {
    __shared__ int s[512];
    int i = blockIdx.x * 512 + threadIdx.x;
    s[threadIdx.x] = (i < n) ? in[i] : 0;
    __syncthreads();
    for (int off = 256; off; off >>= 1) {
        if (threadIdx.x < off) s[threadIdx.x] += s[threadIdx.x + off];
        __syncthreads();
    }
    if (threadIdx.x == 0) bsum[blockIdx.x] = s[0];
}

__global__ __launch_bounds__(512) void scan_bsums(int* bsum, int nb) {
    __shared__ int buf[2][512];
    int t = threadIdx.x;
    int v = (t < nb) ? bsum[t] : 0;
    buf[0][t] = v;
    __syncthreads();
    int src = 0;
    for (int off = 1; off < 512; off <<= 1) {
        int x = buf[src][t];
        if (t >= off) x += buf[src][t - off];
        buf[src ^ 1][t] = x;
        src ^= 1;
        __syncthreads();
    }
    if (t < nb) bsum[t] = buf[src][t] - v;  // exclusive
}

__global__ __launch_bounds__(512) void block_scan_write(const int* __restrict__ cnt,
                                                        const int* __restrict__ bsum, int n,
                                                        int* __restrict__ rowptr) {
    __shared__ int buf[2][512];
    int t = threadIdx.x;
    int i = blockIdx.x * 512 + t;
    int v = (i < n) ? cnt[i] : 0;
    buf[0][t] = v;
    __syncthreads();
    int src = 0;
    for (int off = 1; off < 512; off <<= 1) {
        int x = buf[src][t];
        if (t >= off) x += buf[src][t - off];
        buf[src ^ 1][t] = x;
        src ^= 1;
        __syncthreads();
    }
    int incl = buf[src][t];
    int base = bsum[blockIdx.x];
    if (i < n) rowptr[i] = base + incl - v;
    if (i == n - 1) rowptr[n] = base + incl;
}

__global__ __launch_bounds__(256) void fill_csr(const int* __restrict__ src,
                                                const int* __restrict__ dst, int E,
                                                const int* __restrict__ rowptr,
                                                int* __restrict__ cur, int* __restrict__ col) {
    int e = blockIdx.x * 256 + threadIdx.x;
    if (e < E) {
        int d = dst[e];
        int p = atomicAdd(&cur[d], 1);
        col[rowptr[d] + p] = src[e];
    }
}

__global__ __launch_bounds__(256) void compute_dinv(const int* __restrict__ rowptr, int n,
                                                    float* __restrict__ dinv) {
    int v = blockIdx.x * 256 + threadIdx.x;
    if (v < n) {
        int deg = rowptr[v + 1] - rowptr[v] + 1;  // +1 self loop
        dinv[v] = rsqrtf((float)deg);
    }
}

__global__ __launch_bounds__(64) void graph_bounds(const int* __restrict__ batch, int n, int ng,
                                                   int* __restrict__ gstart) {
    int b = blockIdx.x * 64 + threadIdx.x;
    if (b > ng) return;
    if (b == ng) { gstart[ng] = n; return; }
    int lo = 0, hi = n;
    while (lo < hi) {
        int mid = (lo + hi) >> 1;
        if (batch[mid] < b) lo = mid + 1; else hi = mid;
    }
    gstart[b] = lo;
}

// ---- xs[v] = x[v]*dinv[v] -> bf16 [N][80] (cols 78,79 = 0) ----

__global__ __launch_bounds__(256) void scale_x(const float* __restrict__ x,
                                               const float* __restrict__ dinv,
                                               unsigned short* __restrict__ XS) {
    int idx = blockIdx.x * 256 + threadIdx.x;
    int v = idx / 40, c = idx % 40;
    if (v >= N_NODES) return;
    if (c == 39) {
        *(unsigned int*)(XS + (size_t)v * 80 + 78) = 0u;
        return;
    }
    float dv = dinv[v];
    f32x2 xv = *(const f32x2*)(x + (size_t)v * 78 + c * 2);
    unsigned int pack = ((unsigned int)f2bf(xv.y * dv) << 16) | f2bf(xv.x * dv);
    *(unsigned int*)(XS + (size_t)v * 80 + c * 2) = pack;
}

// ---- aggregation on pre-scaled features: out[v] = dinv[v]*(sum_{u in N(v)} X[u] + X[v]) ----

template <int LD, int NCH, int NPB>
__global__ __launch_bounds__(256) void agg_sum(const unsigned short* __restrict__ X,
                                               const float* __restrict__ dinv,
                                               const int* __restrict__ rowptr,
                                               const int* __restrict__ col,
                                               unsigned short* __restrict__ out) {
    int tid = threadIdx.x;
    if (tid >= NPB * NCH) return;
    int v = blockIdx.x * NPB + tid / NCH;
    int c = tid % NCH;
    if (v >= N_NODES) return;
    u32x4 xv = *(const u32x4*)(X + (size_t)v * LD + c * 8);
    float a0 = bf2f(xv.x & 0xffffu), a1 = bf2f(xv.x >> 16);
    float a2 = bf2f(xv.y & 0xffffu), a3 = bf2f(xv.y >> 16);
    float a4 = bf2f(xv.z & 0xffffu), a5 = bf2f(xv.z >> 16);
    float a6 = bf2f(xv.w & 0xffffu), a7 = bf2f(xv.w >> 16);
    int r0 = rowptr[v], r1 = rowptr[v + 1];
    for (int e = r0; e < r1; ++e) {
        int u = col[e];
        u32x4 xu = *(const u32x4*)(X + (size_t)u * LD + c * 8);
        a0 += bf2f(xu.x & 0xffffu);
        a1 += bf2f(xu.x >> 16);
        a2 += bf2f(xu.y & 0xffffu);
        a3 += bf2f(xu.y >> 16);
        a4 += bf2f(xu.z & 0xffffu);
        a5 += bf2f(xu.z >> 16);
        a6 += bf2f(xu.w & 0xffffu);
        a7 += bf2f(xu.w >> 16);
    }
    float dv = dinv[v];
    u32x4 o;
    o.x = ((unsigned int)f2bf(a1 * dv) << 16) | f2bf(a0 * dv);
    o.y = ((unsigned int)f2bf(a3 * dv) << 16) | f2bf(a2 * dv);
    o.z = ((unsigned int)f2bf(a5 * dv) << 16) | f2bf(a4 * dv);
    o.w = ((unsigned int)f2bf(a7 * dv) << 16) | f2bf(a6 * dv);
    *(u32x4*)(out + (size_t)v * LD + c * 8) = o;
}

// ------- MFMA node GEMM: Cout = relu(A @ W + bias) * dinv[row], bf16 in/out -------

template <int KREAL, int NREAL, int LDA, int LDC, int NF, int KS>
__global__ __launch_bounds__(256) void gemm_mfma_node(const unsigned short* __restrict__ A,
                                                      const float* __restrict__ W,
                                                      const float* __restrict__ bias,
                                                      const float* __restrict__ dinv,
                                                      unsigned short* __restrict__ Cout, int M) {
    __shared__ unsigned short Bs[NF * KS * 64 * 8];
    int tid = threadIdx.x;
    for (int idx = tid; idx < NF * KS * 64; idx += 256) {
        int l = idx & 63, ks = (idx >> 6) % KS, nf = idx / (64 * KS);
        int k0 = ks * 32 + 8 * (l >> 4);
        int cc = nf * 16 + (l & 15);
        short8v t;
#pragma unroll
        for (int j = 0; j < 8; j++) {
            int k = k0 + j;
            float w = (k < KREAL && cc < NREAL) ? W[(size_t)k * NREAL + cc] : 0.f;
            t[j] = (short)f2bf(w);
        }
        *(short8v*)&Bs[idx * 8] = t;
    }
    __syncthreads();

    int lane = tid & 63, wid = tid >> 6;
    int m0 = blockIdx.x * 128 + wid * 32;
    float biasr[NF];
#pragma unroll
    for (int nf = 0; nf < NF; nf++) {
        int cc = nf * 16 + (lane & 15);
        biasr[nf] = (cc < NREAL) ? bias[cc] : 0.f;
    }
    f32x4 acc[2][NF];
#pragma unroll
    for (int mf = 0; mf < 2; mf++)
#pragma unroll
        for (int nf = 0; nf < NF; nf++) acc[mf][nf] = (f32x4){0.f, 0.f, 0.f, 0.f};

    int ra = min(m0 + (lane & 15), M - 1);
    int rb = min(m0 + 16 + (lane & 15), M - 1);
#pragma unroll
    for (int ks = 0; ks < KS; ks++) {
        int koff = ks * 32 + 8 * (lane >> 4);
        short8v a0 = *(const short8v*)(A + (size_t)ra * LDA + koff);
        short8v a1 = *(const short8v*)(A + (size_t)rb * LDA + koff);
#pragma unroll
        for (int nf = 0; nf < NF; nf++) {
            short8v b = *(const short8v*)&Bs[((nf * KS + ks) * 64 + lane) * 8];
            acc[0][nf] = __builtin_amdgcn_mfma_f32_16x16x32_bf16(a0, b, acc[0][nf], 0, 0, 0);
            acc[1][nf] = __builtin_amdgcn_mfma_f32_16x16x32_bf16(a1, b, acc[1][nf], 0, 0, 0);
        }
    }
    float dr[2][4];
#pragma unroll
    for (int mf = 0; mf < 2; mf++)
#pragma unroll
        for (int r = 0; r < 4; r++) {
            int row = m0 + mf * 16 + 4 * (lane >> 4) + r;
            dr[mf][r] = dinv[min(row, M - 1)];
        }
#pragma unroll
    for (int mf = 0; mf < 2; mf++) {
#pragma unroll
        for (int nf = 0; nf < NF; nf++) {
            int cc = nf * 16 + (lane & 15);
#pragma unroll
            for (int r = 0; r < 4; r++) {
                int row = m0 + mf * 16 + 4 * (lane >> 4) + r;
                float v = fmaxf(acc[mf][nf][r] + biasr[nf], 0.f) * dr[mf][r];
                unsigned short o = (cc < NREAL) ? f2bf(v) : (unsigned short)0;
                if (row < M) Cout[(size_t)row * LDC + cc] = o;
            }
        }
    }
}

// ------- layer-3 GEMM fused with per-graph segment-max; grid (5 col-blocks, 512 graphs) ----

__global__ __launch_bounds__(256) void seg_gemm_max(const unsigned short* __restrict__ A,
                                                    const float* __restrict__ W3,
                                                    const float* __restrict__ b3,
                                                    const int* __restrict__ gstart,
                                                    float* __restrict__ g3) {
    __shared__ unsigned short Bs[4 * 5 * 64 * 8];  // 20 KB
    __shared__ float wmax[4][64];
    int g = blockIdx.y;
    int c0 = blockIdx.x * 64;
    int r0 = gstart[g], r1 = gstart[g + 1];
    int tid = threadIdx.x, lane = tid & 63, wid = tid >> 6;

    for (int idx = tid; idx < 1280; idx += 256) {
        int l = idx & 63, ks = (idx >> 6) % 5, nf = idx / 320;
        int k0 = ks * 32 + 8 * (l >> 4);
        int cc = c0 + nf * 16 + (l & 15);
        short8v t;
#pragma unroll
        for (int j = 0; j < 8; j++) {
            int k = k0 + j;
            float w = (k < 156 && cc < 312) ? W3[(size_t)k * 312 + cc] : 0.f;
            t[j] = (short)f2bf(w);
        }
        *(short8v*)&Bs[idx * 8] = t;
    }
    __syncthreads();

    float biasr[4], cmax[4];
#pragma unroll
    for (int nf = 0; nf < 4; nf++) {
        int cc = c0 + nf * 16 + (lane & 15);
        biasr[nf] = (cc < 312) ? b3[cc] : 0.f;
        cmax[nf] = 0.f;
    }

    for (int mt = r0 + wid * 32; mt < r1; mt += 128) {
        f32x4 acc[2][4];
#pragma unroll
        for (int mf = 0; mf < 2; mf++)
#pragma unroll
            for (int nf = 0; nf < 4; nf++) acc[mf][nf] = (f32x4){0.f, 0.f, 0.f, 0.f};
        int ra = min(mt + (lane & 15), N_NODES - 1);
        int rb = min(mt + 16 + (lane & 15), N_NODES - 1);
#pragma unroll
        for (int ks = 0; ks < 5; ks++) {
            int koff = ks * 32 + 8 * (lane >> 4);
            short8v a0 = *(const short8v*)(A + (size_t)ra * 160 + koff);
            short8v a1 = *(const short8v*)(A + (size_t)rb * 160 + koff);
#pragma unroll
            for (int nf = 0; nf < 4; nf++) {
                short8v b = *(const short8v*)&Bs[((nf * 5 + ks) * 64 + lane) * 8];
                acc[0][nf] = __builtin_amdgcn_mfma_f32_16x16x32_bf16(a0, b, acc[0][nf], 0, 0, 0);
                acc[1][nf] = __builtin_amdgcn_mfma_f32_16x16x32_bf16(a1, b, acc[1][nf], 0, 0, 0);
            }
        }
#pragma unroll
        for (int mf = 0; mf < 2; mf++) {
#pragma unroll
            for (int nf = 0; nf < 4; nf++) {
#pragma unroll
                for (int r = 0; r < 4; r++) {
                    int row = mt + mf * 16 + 4 * (lane >> 4) + r;
                    float v = fmaxf(acc[mf][nf][r] + biasr[nf], 0.f);
                    if (row < r1) cmax[nf] = fmaxf(cmax[nf], v);
                }
            }
        }
    }
#pragma unroll
    for (int nf = 0; nf < 4; nf++) {
        float m = cmax[nf];
        m = fmaxf(m, __shfl_xor(m, 16));
        m = fmaxf(m, __shfl_xor(m, 32));
        if (lane < 16) wmax[wid][nf * 16 + lane] = m;
    }
    __syncthreads();
    if (tid < 64) {
        float m = fmaxf(fmaxf(wmax[0][tid], wmax[1][tid]), fmaxf(wmax[2][tid], wmax[3][tid]));
        int cc = c0 + tid;
        if (cc < 312) g3[(size_t)g * 312 + cc] = m;
    }
}

// ---------------- head GEMMs: split-K, atomicAdd into bias-initialized C ----------------

__global__ __launch_bounds__(256) void init_bias_all(float* __restrict__ gg,
                                                     const float* __restrict__ bg1,
                                                     float* __restrict__ xc,
                                                     const float* __restrict__ bg2,
                                                     const float* __restrict__ bxt,
                                                     float* __restrict__ f1,
                                                     const float* __restrict__ bf1,
                                                     float* __restrict__ f2,
                                                     const float* __restrict__ bf2) {
    int idx = blockIdx.x * 256 + threadIdx.x;
    int row = idx / 2816, c = idx % 2816;
    if (row >= N_GRAPHS) return;
    if (c < 1024) gg[(size_t)row * 1024 + c] = bg1[c];
    else if (c < 1280) {
        int j = c - 1024;
        xc[(size_t)row * 256 + j] = (j < 128) ? bg2[j] : bxt[j - 128];
    } else if (c < 2304)
        f1[(size_t)row * 1024 + (c - 1280)] = bf1[c - 1280];
    else
        f2[(size_t)row * 512 + (c - 2304)] = bf2[c - 2304];
}

template <int RELUA>
__global__ __launch_bounds__(256) void gemm_splitk(const float* __restrict__ A,
                                                   const float* __restrict__ B,
                                                   float* __restrict__ C, int M, int N, int K,
                                                   int ldc, int Kc) {
    __shared__ float As[16][17];
    __shared__ float Bs[16][64];
    int bx = blockIdx.x, by = blockIdx.y, bz = blockIdx.z;
    int tid = threadIdx.x;
    int lane = tid & 63, wy = tid >> 6;
    int n0 = bx * 64, m0 = by * 16;
    int k0 = bz * Kc, k1 = min(K, k0 + Kc);
    float acc[4] = {0.f, 0.f, 0.f, 0.f};
    for (int kt = k0; kt < k1; kt += 16) {
        {
            int r = tid >> 4, kk = tid & 15;
            int gm = m0 + r, gk = kt + kk;
            float v = (gk < k1 && gm < M) ? A[(size_t)gm * K + gk] : 0.f;
            if (RELUA) v = fmaxf(v, 0.f);
            As[kk][r] = v;
        }
#pragma unroll
        for (int l = 0; l < 4; l++) {
            int kk = wy + l * 4;
            int gk = kt + kk, gn = n0 + lane;
            Bs[kk][lane] = (gk < k1 && gn < N) ? B[(size_t)gk * N + gn] : 0.f;
        }
        __syncthreads();
#pragma unroll
        for (int kk = 0; kk < 16; kk++) {
            float b = Bs[kk][lane];
#pragma unroll
            for (int r = 0; r < 4; r++) acc[r] += As[kk][wy * 4 + r] * b;
        }
        __syncthreads();
    }
    int gn = n0 + lane;
    if (gn < N) {
#pragma unroll
        for (int r = 0; r < 4; r++) {
            int gm = m0 + wy * 4 + r;
            if (gm < M) atomicAdd(&C[(size_t)gm * ldc + gn], acc[r]);
        }
    }
}

// ---------------- conv head via MFMA ----------------
// A_n[t, o*8+k] = sum_{i: tg[i]=t} convw[o,i,k]  ==  onehot_n[26x1000] @ CW[1000x256]
// c_n[o, w]     = sum_{t,k} emb[t, w+k] * A_n[t, o*8+k]  ==  A''_n[32x208] @ E[208x121]
// CWf / Ef are fragment-ordered bf16 operands built once per launch.

__global__ __launch_bounds__(256) void prep_cwf(const float* __restrict__ convw,
                                                unsigned short* __restrict__ CWf) {
    int idx = blockIdx.x * 256 + threadIdx.x;  // [0, 32768): (ks, nf, lane)
    int ks = idx >> 10, nf = (idx >> 6) & 15, lane = idx & 63;
    int k0 = ks * 32 + 8 * (lane >> 4);
    int c = nf * 16 + (lane & 15);
    int o = c >> 3, kk = c & 7;
    short8v t;
#pragma unroll
    for (int j = 0; j < 8; j++) {
        int k = k0 + j;
        float v = (k < 1000) ? convw[(size_t)o * 8000 + k * 8 + kk] : 0.f;
        t[j] = (short)f2bf(v);
    }
    *(short8v*)&CWf[(size_t)idx * 8] = t;
}

__global__ __launch_bounds__(256) void prep_ef(const float* __restrict__ emb,
                                               unsigned short* __restrict__ Ef) {
    int idx = blockIdx.x * 256 + threadIdx.x;  // [0, 3584): (ks, nf, lane)
    if (idx >= 7 * 8 * 64) return;
    int ks = idx >> 9, nf = (idx >> 6) & 7, lane = idx & 63;
    int j0 = ks * 32 + 8 * (lane >> 4);
    int w = nf * 16 + (lane & 15);
    short8v t;
#pragma unroll
    for (int j8 = 0; j8 < 8; j8++) {
        int j = j0 + j8;
        float v = (j < 208 && w < 121) ? emb[(size_t)(j >> 3) * 128 + w + (j & 7)] : 0.f;
        t[j8] = (short)f2bf(v);
    }
    *(short8v*)&Ef[(size_t)idx * 8] = t;
}

__global__ __launch_bounds__(256) void conv_mfma(const int* __restrict__ target,
                                                 const unsigned short* __restrict__ CWf,
                                                 const unsigned short* __restrict__ Ef,
                                                 const float* __restrict__ convb,
                                                 float* __restrict__ c) {
    __shared__ int tg[1024];
    __shared__ unsigned short A_lds[32 * 256];  // 16 KB
    int n = blockIdx.x;
    int tid = threadIdx.x, lane = tid & 63, wid = tid >> 6;
    int hi = lane >> 4, l15 = lane & 15;
    for (int i = tid; i < 1024; i += 256) tg[i] = (i < 1000) ? target[n * 1000 + i] : -1;
    __syncthreads();

    // phase A: A = onehot @ CW; wave owns 4 of 16 col-frags
    f32x4 acc[2][4];
#pragma unroll
    for (int mf = 0; mf < 2; mf++)
#pragma unroll
        for (int nf = 0; nf < 4; nf++) acc[mf][nf] = (f32x4){0.f, 0.f, 0.f, 0.f};
    int r0 = l15, r1 = l15 + 16;
    for (int ks = 0; ks < 32; ks++) {
        int kk = ks * 32 + 8 * hi;
        i32x4 ta = *(const i32x4*)&tg[kk];
        i32x4 tb = *(const i32x4*)&tg[kk + 4];
        short8v a0, a1;
        a0[0] = (ta.x == r0) ? (short)0x3F80 : (short)0;
        a0[1] = (ta.y == r0) ? (short)0x3F80 : (short)0;
        a0[2] = (ta.z == r0) ? (short)0x3F80 : (short)0;
        a0[3] = (ta.w == r0) ? (short)0x3F80 : (short)0;
        a0[4] = (tb.x == r0) ? (short)0x3F80 : (short)0;
        a0[5] = (tb.y == r0) ? (short)0x3F80 : (short)0;
        a0[6] = (tb.z == r0) ? (short)0x3F80 : (short)0;
        a0[7] = (tb.w == r0) ? (short)0x3F80 : (short)0;
        a1[0] = (ta.x == r1) ? (short)0x3F80 : (short)0;
        a1[1] = (ta.y == r1) ? (short)0x3F80 : (short)0;
        a1[2] = (ta.z == r1) ? (short)0x3F80 : (short)0;
        a1[3] = (ta.w == r1) ? (short)0x3F80 : (short)0;
        a1[4] = (tb.x == r1) ? (short)0x3F80 : (short)0;
        a1[5] = (tb.y == r1) ? (short)0x3F80 : (short)0;
        a1[6] = (tb.z == r1) ? (short)0x3F80 : (short)0;
        a1[7] = (tb.w == r1) ? (short)0x3F80 : (short)0;
#pragma unroll
        for (int nf = 0; nf < 4; nf++) {
            short8v b = *(const short8v*)&CWf[((size_t)(ks * 16 + wid * 4 + nf) * 64 + lane) * 8];
            acc[0][nf] = __builtin_amdgcn_mfma_f32_16x16x32_bf16(a0, b, acc[0][nf], 0, 0, 0);
            acc[1][nf] = __builtin_amdgcn_mfma_f32_16x16x32_bf16(a1, b, acc[1][nf], 0, 0, 0);
        }
    }
    // write A to LDS (rows >= 26 are zero by construction)
#pragma unroll
    for (int mf = 0; mf < 2; mf++)
#pragma unroll
        for (int nf = 0; nf < 4; nf++) {
            int col = (wid * 4 + nf) * 16 + l15;
#pragma unroll
            for (int r = 0; r < 4; r++) {
                int row = 16 * mf + 4 * hi + r;
                A_lds[row * 256 + col] = f2bf(acc[mf][nf][r]);
            }
        }
    __syncthreads();

    // phase B: c = A'' @ E; wave owns 2 of 8 col-frags (w range)
    f32x4 acc2[2][2];
#pragma unroll
    for (int mf = 0; mf < 2; mf++)
#pragma unroll
        for (int nf = 0; nf < 2; nf++) acc2[mf][nf] = (f32x4){0.f, 0.f, 0.f, 0.f};
#pragma unroll
    for (int ks = 0; ks < 7; ks++) {
        int j0 = ks * 32 + 8 * hi;
        int t = j0 >> 3;
        short8v a0 = *(const short8v*)&A_lds[t * 256 + l15 * 8];         // o = l15
        short8v a1 = *(const short8v*)&A_lds[t * 256 + (l15 + 16) * 8];  // o = l15+16
#pragma unroll
        for (int nf = 0; nf < 2; nf++) {
            short8v b = *(const short8v*)&Ef[((size_t)(ks * 8 + wid * 2 + nf) * 64 + lane) * 8];
            acc2[0][nf] = __builtin_amdgcn_mfma_f32_16x16x32_bf16(a0, b, acc2[0][nf], 0, 0, 0);
            acc2[1][nf] = __builtin_amdgcn_mfma_f32_16x16x32_bf16(a1, b, acc2[1][nf], 0, 0, 0);
        }
    }
#pragma unroll
    for (int mf = 0; mf < 2; mf++)
#pragma unroll
        for (int nf = 0; nf < 2; nf++) {
            int w = (wid * 2 + nf) * 16 + l15;
            if (w < 121) {
#pragma unroll
                for (int r = 0; r < 4; r++) {
                    int o = 16 * mf + 4 * hi + r;
                    c[(size_t)n * 3872 + o * 121 + w] = acc2[mf][nf][r] + convb[o];
                }
            }
        }
}

// ---------------- final N=1 matvec (relu on load) ----------------

__global__ __launch_bounds__(256) void rowdot(const float* __restrict__ f2,
                                              const float* __restrict__ Wo,
                                              const float* __restrict__ bo,
                                              float* __restrict__ out, int M, int K) {
    int row = blockIdx.x * 4 + (threadIdx.x >> 6);
    int lane = threadIdx.x & 63;
    if (row >= M) return;
    float acc = 0.f;
    for (int k = lane; k < K; k += 64) acc += fmaxf(f2[(size_t)row * K + k], 0.f) * Wo[k];
    for (int off = 32; off; off >>= 1) acc += __shfl_down(acc, off);
    if (lane == 0) out[row] = acc + bo[0];
}

// ---------------- launch ----------------

extern "C" void kernel_launch(void* const* d_in, const int* in_sizes, int n_in, void* d_out,
                              int out_size, void* d_ws, size_t ws_size, hipStream_t stream) {
    const float* x = (const float*)d_in[0];
    const int* ei = (const int*)d_in[1];
    const int* batch = (const int*)d_in[2];
    const int* target = (const int*)d_in[3];
    const float* W1 = (const float*)d_in[4];
    const float* b1 = (const float*)d_in[5];
    const float* W2 = (const float*)d_in[6];
    const float* b2 = (const float*)d_in[7];
    const float* W3 = (const float*)d_in[8];
    const float* b3 = (const float*)d_in[9];
    const float* Wg1 = (const float*)d_in[10];
    const float* bg1 = (const float*)d_in[11];
    const float* Wg2 = (const float*)d_in[12];
    const float* bg2 = (const float*)d_in[13];
    const float* emb = (const float*)d_in[14];
    const float* convw = (const float*)d_in[15];
    const float* convb = (const float*)d_in[16];
    const float* Wxt = (const float*)d_in[17];
    const float* bxt = (const float*)d_in[18];
    const float* Wf1 = (const float*)d_in[19];
    const float* bf1 = (const float*)d_in[20];
    const float* Wf2 = (const float*)d_in[21];
    const float* bf2 = (const float*)d_in[22];
    const float* Wo = (const float*)d_in[23];
    const float* bo = (const float*)d_in[24];
    float* out = (float*)d_out;

    const int N = N_NODES, E = N_EDGES;
    const int NB = (N + 511) / 512;

    char* ws = (char*)d_ws;
    size_t off = 0;
    auto alloc = [&](size_t bytes) -> char* {
        char* p = ws + off;
        off = (off + bytes + 255) & ~(size_t)255;
        return p;
    };
    int* cnt = (int*)alloc((size_t)N * 2 * 4);  // cnt + cur, one memset
    int* cur = cnt + N;
    int* rowptr = (int*)alloc((size_t)(N + 1) * 4);
    int* bsum = (int*)alloc(512 * 4);
    int* col = (int*)alloc((size_t)E * 4);
    float* dinv = (float*)alloc((size_t)N * 4);
    int* gstart = (int*)alloc((N_GRAPHS + 1) * 4);
    float* g3 = (float*)alloc((size_t)N_GRAPHS * 312 * 4);
    float* gg = (float*)alloc((size_t)N_GRAPHS * 1024 * 4);
    float* cbuf = (float*)alloc((size_t)N_GRAPHS * 3872 * 4);
    float* xc = (float*)alloc((size_t)N_GRAPHS * 256 * 4);
    float* f1 = (float*)alloc((size_t)N_GRAPHS * 1024 * 4);
    float* f2 = (float*)alloc((size_t)N_GRAPHS * 512 * 4);
    unsigned short* CWf = (unsigned short*)alloc((size_t)32768 * 8 * 2);  // 512 KB
    unsigned short* Ef = (unsigned short*)alloc((size_t)3584 * 8 * 2);    // 56 KB
    unsigned short* U = (unsigned short*)alloc((size_t)N * 160 * 2 + 512);
    unsigned short* P160 = (unsigned short*)alloc((size_t)N * 160 * 2 + 512);
    unsigned short* H1 = U + (size_t)N * 80;  // [N,80] second half of U

    const int* srcp = ei;
    const int* dstp = ei + E;

    // CSR + norm
    hipMemsetAsync(cnt, 0, (size_t)N * 2 * 4, stream);
    count_edges<<<(E + 255) / 256, 256, 0, stream>>>(dstp, E, cnt);
    block_reduce<<<NB, 512, 0, stream>>>(cnt, N, bsum);
    scan_bsums<<<1, 512, 0, stream>>>(bsum, NB);
    block_scan_write<<<NB, 512, 0, stream>>>(cnt, bsum, N, rowptr);
    fill_csr<<<(E + 255) / 256, 256, 0, stream>>>(srcp, dstp, E, rowptr, cur, col);
    compute_dinv<<<(N + 255) / 256, 256, 0, stream>>>(rowptr, N, dinv);
    graph_bounds<<<(N_GRAPHS + 1 + 63) / 64, 64, 0, stream>>>(batch, N, N_GRAPHS, gstart);

    // bias-init split-K outputs (one kernel)
    init_bias_all<<<(N_GRAPHS * 2816 + 255) / 256, 256, 0, stream>>>(gg, bg1, xc, bg2, bxt, f1,
                                                                     bf1, f2, bf2);
    // conv operand prep
    prep_cwf<<<128, 256, 0, stream>>>(convw, CWf);
    prep_ef<<<14, 256, 0, stream>>>(emb, Ef);

    const int MB = (N + 127) / 128;  // 1563

    // layer 1: XS = x*dinv (P160); A1 = aggsum(XS) (U80); h1' = relu(A1@W1+b1)*dinv (H1)
    scale_x<<<(N * 40 + 255) / 256, 256, 0, stream>>>(x, dinv, P160);
    agg_sum<80, 10, 25><<<(N + 24) / 25, 256, 0, stream>>>(P160, dinv, rowptr, col, U);
    gemm_mfma_node<78, 78, 80, 80, 5, 3><<<MB, 256, 0, stream>>>(U, W1, b1, dinv, H1, N);
    // layer 2: A2 = aggsum(h1') (P160[:,:80]); h2' = relu(A2@W2+b2)*dinv (U as [N,160])
    agg_sum<80, 10, 25><<<(N + 24) / 25, 256, 0, stream>>>(H1, dinv, rowptr, col, P160);
    gemm_mfma_node<78, 156, 80, 160, 10, 3><<<MB, 256, 0, stream>>>(P160, W2, b2, dinv, U, N);
    // layer 3: A3 = aggsum(h2') (P160 [N,160]); fused GEMM + per-graph segment max
    agg_sum<160, 20, 12><<<(N + 11) / 12, 256, 0, stream>>>(U, dinv, rowptr, col, P160);
    seg_gemm_max<<<dim3(5, N_GRAPHS), 256, 0, stream>>>(P160, W3, b3, gstart, g3);

    // graph head
    gemm_splitk<0><<<dim3(16, 32, 2), 256, 0, stream>>>(g3, Wg1, gg, 512, 1024, 312, 1024, 160);
    gemm_splitk<1><<<dim3(2, 32, 8), 256, 0, stream>>>(gg, Wg2, xc, 512, 128, 1024, 256, 128);

    // conv head (MFMA)
    conv_mfma<<<N_GRAPHS, 256, 0, stream>>>(target, CWf, Ef, convb, cbuf);
    gemm_splitk<0><<<dim3(2, 32, 16), 256, 0, stream>>>(cbuf, Wxt, xc + 128, 512, 128, 3872, 256, 256);

    // final MLP
    gemm_splitk<0><<<dim3(16, 32, 2), 256, 0, stream>>>(xc, Wf1, f1, 512, 1024, 256, 1024, 128);
    gemm_splitk<1><<<dim3(8, 32, 8), 256, 0, stream>>>(f1, Wf2, f2, 512, 512, 1024, 512, 128);
    rowdot<<<(N_GRAPHS + 3) / 4, 256, 0, stream>>>(f2, Wo, bo, out, N_GRAPHS, 512);
}

// Round 8
// 690.848 us; speedup vs baseline: 2.0266x; 1.1037x over previous
//
#include <hip/hip_runtime.h>
#include <hip/hip_bf16.h>

#define N_NODES 200000
#define N_EDGES 800000
#define N_GRAPHS 512

typedef __attribute__((ext_vector_type(8))) short short8v;
typedef __attribute__((ext_vector_type(4))) float f32x4;
typedef __attribute__((ext_vector_type(2))) float f32x2;
typedef __attribute__((ext_vector_type(2))) unsigned int u32x2;
typedef __attribute__((ext_vector_type(4))) unsigned int u32x4;
typedef __attribute__((ext_vector_type(4))) int i32x4;

__device__ inline float bf2f(unsigned int u) {
    union { unsigned int i; float f; } c;
    c.i = u << 16;
    return c.f;
}
__device__ inline unsigned short f2bf(float f) {
    union { __hip_bfloat16 h; unsigned short u; } c;
    c.h = __float2bfloat16(f);
    return c.u;
}

// ---------------- CSR build ----------------

__global__ __launch_bounds__(256) void count_edges(const int* __restrict__ dst, int E,
                                                   int* __restrict__ cnt) {
    int e = blockIdx.x * 256 + threadIdx.x;
    if (e < E) atomicAdd(&cnt[dst[e]], 1);
}

__global__ __launch_bounds__(512) void block_reduce(const int* __restrict__ in, int n,
                                                    int* __restrict__ bsum) {
    __shared__ int s[512];
    int i = blockIdx.x * 512 + threadIdx.x;
    s[threadIdx.x] = (i < n) ? in[i] : 0;
    __syncthreads();
    for (int off = 256; off; off >>= 1) {
        if (threadIdx.x < off) s[threadIdx.x] += s[threadIdx.x + off];
        __syncthreads();
    }
    if (threadIdx.x == 0) bsum[blockIdx.x] = s[0];
}

__global__ __launch_bounds__(512) void scan_bsums(int* bsum, int nb) {
    __shared__ int buf[2][512];
    int t = threadIdx.x;
    int v = (t < nb) ? bsum[t] : 0;
    buf[0][t] = v;
    __syncthreads();
    int src = 0;
    for (int off = 1; off < 512; off <<= 1) {
        int x = buf[src][t];
        if (t >= off) x += buf[src][t - off];
        buf[src ^ 1][t] = x;
        src ^= 1;
        __syncthreads();
    }
    if (t < nb) bsum[t] = buf[src][t] - v;  // exclusive
}

__global__ __launch_bounds__(512) void block_scan_write(const int* __restrict__ cnt,
                                                        const int* __restrict__ bsum, int n,
                                                        int* __restrict__ rowptr) {
    __shared__ int buf[2][512];
    int t = threadIdx.x;
    int i = blockIdx.x * 512 + t;
    int v = (i < n) ? cnt[i] : 0;
    buf[0][t] = v;
    __syncthreads();
    int src = 0;
    for (int off = 1; off < 512; off <<= 1) {
        int x = buf[src][t];
        if (t >= off) x += buf[src][t - off];
        buf[src ^ 1][t] = x;
        src ^= 1;
        __syncthreads();
    }
    int incl = buf[src][t];
    int base = bsum[blockIdx.x];
    if (i < n) rowptr[i] = base + incl - v;
    if (i == n - 1) rowptr[n] = base + incl;
}

__global__ __launch_bounds__(256) void fill_csr(const int* __restrict__ src,
                                                const int* __restrict__ dst, int E,
                                                const int* __restrict__ rowptr,
                                                int* __restrict__ cur, int* __restrict__ col) {
    int e = blockIdx.x * 256 + threadIdx.x;
    if (e < E) {
        int d = dst[e];
        int p = atomicAdd(&cur[d], 1);
        col[rowptr[d] + p] = src[e];
    }
}

__global__ __launch_bounds__(256) void compute_dinv(const int* __restrict__ rowptr, int n,
                                                    float* __restrict__ dinv) {
    int v = blockIdx.x * 256 + threadIdx.x;
    if (v < n) {
        int deg = rowptr[v + 1] - rowptr[v] + 1;  // +1 self loop
        dinv[v] = rsqrtf((float)deg);
    }
}

__global__ __launch_bounds__(64) void graph_bounds(const int* __restrict__ batch, int n, int ng,
                                                   int* __restrict__ gstart) {
    int b = blockIdx.x * 64 + threadIdx.x;
    if (b > ng) return;
    if (b == ng) { gstart[ng] = n; return; }
    int lo = 0, hi = n;
    while (lo < hi) {
        int mid = (lo + hi) >> 1;
        if (batch[mid] < b) lo = mid + 1; else hi = mid;
    }
    gstart[b] = lo;
}

// ---- xs[v] = x[v]*dinv[v] -> bf16 [N][80] (cols 78,79 = 0) ----

__global__ __launch_bounds__(256) void scale_x(const float* __restrict__ x,
                                               const float* __restrict__ dinv,
                                               unsigned short* __restrict__ XS) {
    int idx = blockIdx.x * 256 + threadIdx.x;
    int v = idx / 40, c = idx % 40;
    if (v >= N_NODES) return;
    if (c == 39) {
        *(unsigned int*)(XS + (size_t)v * 80 + 78) = 0u;
        return;
    }
    float dv = dinv[v];
    f32x2 xv = *(const f32x2*)(x + (size_t)v * 78 + c * 2);
    unsigned int pack = ((unsigned int)f2bf(xv.y * dv) << 16) | f2bf(xv.x * dv);
    *(unsigned int*)(XS + (size_t)v * 80 + c * 2) = pack;
}

// ---- aggregation on pre-scaled features: out[v] = dinv[v]*(sum_{u in N(v)} X[u] + X[v]) ----

template <int LD, int NCH, int NPB>
__global__ __launch_bounds__(256) void agg_sum(const unsigned short* __restrict__ X,
                                               const float* __restrict__ dinv,
                                               const int* __restrict__ rowptr,
                                               const int* __restrict__ col,
                                               unsigned short* __restrict__ out) {
    int tid = threadIdx.x;
    if (tid >= NPB * NCH) return;
    int v = blockIdx.x * NPB + tid / NCH;
    int c = tid % NCH;
    if (v >= N_NODES) return;
    u32x4 xv = *(const u32x4*)(X + (size_t)v * LD + c * 8);
    float a0 = bf2f(xv.x & 0xffffu), a1 = bf2f(xv.x >> 16);
    float a2 = bf2f(xv.y & 0xffffu), a3 = bf2f(xv.y >> 16);
    float a4 = bf2f(xv.z & 0xffffu), a5 = bf2f(xv.z >> 16);
    float a6 = bf2f(xv.w & 0xffffu), a7 = bf2f(xv.w >> 16);
    int r0 = rowptr[v], r1 = rowptr[v + 1];
    for (int e = r0; e < r1; ++e) {
        int u = col[e];
        u32x4 xu = *(const u32x4*)(X + (size_t)u * LD + c * 8);
        a0 += bf2f(xu.x & 0xffffu);
        a1 += bf2f(xu.x >> 16);
        a2 += bf2f(xu.y & 0xffffu);
        a3 += bf2f(xu.y >> 16);
        a4 += bf2f(xu.z & 0xffffu);
        a5 += bf2f(xu.z >> 16);
        a6 += bf2f(xu.w & 0xffffu);
        a7 += bf2f(xu.w >> 16);
    }
    float dv = dinv[v];
    u32x4 o;
    o.x = ((unsigned int)f2bf(a1 * dv) << 16) | f2bf(a0 * dv);
    o.y = ((unsigned int)f2bf(a3 * dv) << 16) | f2bf(a2 * dv);
    o.z = ((unsigned int)f2bf(a5 * dv) << 16) | f2bf(a4 * dv);
    o.w = ((unsigned int)f2bf(a7 * dv) << 16) | f2bf(a6 * dv);
    *(u32x4*)(out + (size_t)v * LD + c * 8) = o;
}

// ---- one-time weight -> fragment-ordered bf16 conversion ----
// Wf[((nf*KS+ks)*64+lane)*8 + j] = bf16(W[(ks*32 + 8*(lane>>4) + j) * NREAL + nf*16 + (lane&15)])

template <int KREAL, int NREAL, int KS, int NF>
__global__ __launch_bounds__(256) void prep_wf(const float* __restrict__ W,
                                               unsigned short* __restrict__ Wf) {
    int idx = blockIdx.x * 256 + threadIdx.x;
    if (idx >= NF * KS * 64) return;
    int lane = idx & 63, ks = (idx >> 6) % KS, nf = idx / (64 * KS);
    int k0 = ks * 32 + 8 * (lane >> 4);
    int cc = nf * 16 + (lane & 15);
    short8v t;
#pragma unroll
    for (int j = 0; j < 8; j++) {
        int k = k0 + j;
        float w = (k < KREAL && cc < NREAL) ? W[(size_t)k * NREAL + cc] : 0.f;
        t[j] = (short)f2bf(w);
    }
    *(short8v*)&Wf[(size_t)idx * 8] = t;
}

// ------- MFMA node GEMM: Cout = relu(A @ W + bias) * dinv[row], bf16 in/out -------
// Wf pre-converted fragment-ordered bf16; LDS staged via coalesced 16B copies.

template <int NREAL, int LDA, int LDC, int NF, int KS>
__global__ __launch_bounds__(256) void gemm_mfma_node(const unsigned short* __restrict__ A,
                                                      const unsigned short* __restrict__ Wf,
                                                      const float* __restrict__ bias,
                                                      const float* __restrict__ dinv,
                                                      unsigned short* __restrict__ Cout, int M) {
    __shared__ unsigned short Bs[NF * KS * 64 * 8];
    int tid = threadIdx.x;
    for (int idx = tid; idx < NF * KS * 64; idx += 256)
        *(short8v*)&Bs[idx * 8] = *(const short8v*)&Wf[(size_t)idx * 8];
    __syncthreads();

    int lane = tid & 63, wid = tid >> 6;
    int m0 = blockIdx.x * 128 + wid * 32;
    float biasr[NF];
#pragma unroll
    for (int nf = 0; nf < NF; nf++) {
        int cc = nf * 16 + (lane & 15);
        biasr[nf] = (cc < NREAL) ? bias[cc] : 0.f;
    }
    f32x4 acc[2][NF];
#pragma unroll
    for (int mf = 0; mf < 2; mf++)
#pragma unroll
        for (int nf = 0; nf < NF; nf++) acc[mf][nf] = (f32x4){0.f, 0.f, 0.f, 0.f};

    int ra = min(m0 + (lane & 15), M - 1);
    int rb = min(m0 + 16 + (lane & 15), M - 1);
#pragma unroll
    for (int ks = 0; ks < KS; ks++) {
        int koff = ks * 32 + 8 * (lane >> 4);
        short8v a0 = *(const short8v*)(A + (size_t)ra * LDA + koff);
        short8v a1 = *(const short8v*)(A + (size_t)rb * LDA + koff);
#pragma unroll
        for (int nf = 0; nf < NF; nf++) {
            short8v b = *(const short8v*)&Bs[((nf * KS + ks) * 64 + lane) * 8];
            acc[0][nf] = __builtin_amdgcn_mfma_f32_16x16x32_bf16(a0, b, acc[0][nf], 0, 0, 0);
            acc[1][nf] = __builtin_amdgcn_mfma_f32_16x16x32_bf16(a1, b, acc[1][nf], 0, 0, 0);
        }
    }
    float dr[2][4];
#pragma unroll
    for (int mf = 0; mf < 2; mf++)
#pragma unroll
        for (int r = 0; r < 4; r++) {
            int row = m0 + mf * 16 + 4 * (lane >> 4) + r;
            dr[mf][r] = dinv[min(row, M - 1)];
        }
#pragma unroll
    for (int mf = 0; mf < 2; mf++) {
#pragma unroll
        for (int nf = 0; nf < NF; nf++) {
            int cc = nf * 16 + (lane & 15);
#pragma unroll
            for (int r = 0; r < 4; r++) {
                int row = m0 + mf * 16 + 4 * (lane >> 4) + r;
                float v = fmaxf(acc[mf][nf][r] + biasr[nf], 0.f) * dr[mf][r];
                unsigned short o = (cc < NREAL) ? f2bf(v) : (unsigned short)0;
                if (row < M) Cout[(size_t)row * LDC + cc] = o;
            }
        }
    }
}

// ------- layer-3 GEMM fused with per-graph segment-max ----
// 1D grid 2560: bx = id>>9 (col-block of 64), g = id&511 (graph). All 5 col-blocks of a
// graph share XCD (512 % 8 == 0) -> A rows L2-hit after first touch.

__global__ __launch_bounds__(256) void seg_gemm_max(const unsigned short* __restrict__ A,
                                                    const unsigned short* __restrict__ Wf3,
                                                    const float* __restrict__ b3,
                                                    const int* __restrict__ gstart,
                                                    float* __restrict__ g3) {
    __shared__ unsigned short Bs[4 * 5 * 64 * 8];  // 20 KB
    __shared__ float wmax[4][64];
    int g = blockIdx.x & 511;
    int bx = blockIdx.x >> 9;
    int c0 = bx * 64;
    int r0 = gstart[g], r1 = gstart[g + 1];
    int tid = threadIdx.x, lane = tid & 63, wid = tid >> 6;

    const unsigned short* src = Wf3 + (size_t)bx * 4 * 5 * 64 * 8;
    for (int idx = tid; idx < 1280; idx += 256)
        *(short8v*)&Bs[idx * 8] = *(const short8v*)&src[(size_t)idx * 8];
    __syncthreads();

    float biasr[4], cmax[4];
#pragma unroll
    for (int nf = 0; nf < 4; nf++) {
        int cc = c0 + nf * 16 + (lane & 15);
        biasr[nf] = (cc < 312) ? b3[cc] : 0.f;
        cmax[nf] = 0.f;
    }

    for (int mt = r0 + wid * 32; mt < r1; mt += 128) {
        f32x4 acc[2][4];
#pragma unroll
        for (int mf = 0; mf < 2; mf++)
#pragma unroll
            for (int nf = 0; nf < 4; nf++) acc[mf][nf] = (f32x4){0.f, 0.f, 0.f, 0.f};
        int ra = min(mt + (lane & 15), N_NODES - 1);
        int rb = min(mt + 16 + (lane & 15), N_NODES - 1);
#pragma unroll
        for (int ks = 0; ks < 5; ks++) {
            int koff = ks * 32 + 8 * (lane >> 4);
            short8v a0 = *(const short8v*)(A + (size_t)ra * 160 + koff);
            short8v a1 = *(const short8v*)(A + (size_t)rb * 160 + koff);
#pragma unroll
            for (int nf = 0; nf < 4; nf++) {
                short8v b = *(const short8v*)&Bs[((nf * 5 + ks) * 64 + lane) * 8];
                acc[0][nf] = __builtin_amdgcn_mfma_f32_16x16x32_bf16(a0, b, acc[0][nf], 0, 0, 0);
                acc[1][nf] = __builtin_amdgcn_mfma_f32_16x16x32_bf16(a1, b, acc[1][nf], 0, 0, 0);
            }
        }
#pragma unroll
        for (int mf = 0; mf < 2; mf++) {
#pragma unroll
            for (int nf = 0; nf < 4; nf++) {
#pragma unroll
                for (int r = 0; r < 4; r++) {
                    int row = mt + mf * 16 + 4 * (lane >> 4) + r;
                    float v = fmaxf(acc[mf][nf][r] + biasr[nf], 0.f);
                    if (row < r1) cmax[nf] = fmaxf(cmax[nf], v);
                }
            }
        }
    }
#pragma unroll
    for (int nf = 0; nf < 4; nf++) {
        float m = cmax[nf];
        m = fmaxf(m, __shfl_xor(m, 16));
        m = fmaxf(m, __shfl_xor(m, 32));
        if (lane < 16) wmax[wid][nf * 16 + lane] = m;
    }
    __syncthreads();
    if (tid < 64) {
        float m = fmaxf(fmaxf(wmax[0][tid], wmax[1][tid]), fmaxf(wmax[2][tid], wmax[3][tid]));
        int cc = c0 + tid;
        if (cc < 312) g3[(size_t)g * 312 + cc] = m;
    }
}

// ---------------- head GEMMs: split-K, atomicAdd into bias-initialized C ----------------

__global__ __launch_bounds__(256) void init_bias_all(float* __restrict__ gg,
                                                     const float* __restrict__ bg1,
                                                     float* __restrict__ xc,
                                                     const float* __restrict__ bg2,
                                                     const float* __restrict__ bxt,
                                                     float* __restrict__ f1,
                                                     const float* __restrict__ bf1,
                                                     float* __restrict__ f2,
                                                     const float* __restrict__ bf2) {
    int idx = blockIdx.x * 256 + threadIdx.x;
    int row = idx / 2816, c = idx % 2816;
    if (row >= N_GRAPHS) return;
    if (c < 1024) gg[(size_t)row * 1024 + c] = bg1[c];
    else if (c < 1280) {
        int j = c - 1024;
        xc[(size_t)row * 256 + j] = (j < 128) ? bg2[j] : bxt[j - 128];
    } else if (c < 2304)
        f1[(size_t)row * 1024 + (c - 1280)] = bf1[c - 1280];
    else
        f2[(size_t)row * 512 + (c - 2304)] = bf2[c - 2304];
}

template <int RELUA>
__global__ __launch_bounds__(256) void gemm_splitk(const float* __restrict__ A,
                                                   const float* __restrict__ B,
                                                   float* __restrict__ C, int M, int N, int K,
                                                   int ldc, int Kc) {
    __shared__ float As[16][17];
    __shared__ float Bs[16][64];
    int bx = blockIdx.x, by = blockIdx.y, bz = blockIdx.z;
    int tid = threadIdx.x;
    int lane = tid & 63, wy = tid >> 6;
    int n0 = bx * 64, m0 = by * 16;
    int k0 = bz * Kc, k1 = min(K, k0 + Kc);
    float acc[4] = {0.f, 0.f, 0.f, 0.f};
    for (int kt = k0; kt < k1; kt += 16) {
        {
            int r = tid >> 4, kk = tid & 15;
            int gm = m0 + r, gk = kt + kk;
            float v = (gk < k1 && gm < M) ? A[(size_t)gm * K + gk] : 0.f;
            if (RELUA) v = fmaxf(v, 0.f);
            As[kk][r] = v;
        }
#pragma unroll
        for (int l = 0; l < 4; l++) {
            int kk = wy + l * 4;
            int gk = kt + kk, gn = n0 + lane;
            Bs[kk][lane] = (gk < k1 && gn < N) ? B[(size_t)gk * N + gn] : 0.f;
        }
        __syncthreads();
#pragma unroll
        for (int kk = 0; kk < 16; kk++) {
            float b = Bs[kk][lane];
#pragma unroll
            for (int r = 0; r < 4; r++) acc[r] += As[kk][wy * 4 + r] * b;
        }
        __syncthreads();
    }
    int gn = n0 + lane;
    if (gn < N) {
#pragma unroll
        for (int r = 0; r < 4; r++) {
            int gm = m0 + wy * 4 + r;
            if (gm < M) atomicAdd(&C[(size_t)gm * ldc + gn], acc[r]);
        }
    }
}

// ---------------- conv head via MFMA ----------------

__global__ __launch_bounds__(256) void prep_cwf(const float* __restrict__ convw,
                                                unsigned short* __restrict__ CWf) {
    int idx = blockIdx.x * 256 + threadIdx.x;  // [0, 32768): (ks, nf, lane)
    int ks = idx >> 10, nf = (idx >> 6) & 15, lane = idx & 63;
    int k0 = ks * 32 + 8 * (lane >> 4);
    int c = nf * 16 + (lane & 15);
    int o = c >> 3, kk = c & 7;
    short8v t;
#pragma unroll
    for (int j = 0; j < 8; j++) {
        int k = k0 + j;
        float v = (k < 1000) ? convw[(size_t)o * 8000 + k * 8 + kk] : 0.f;
        t[j] = (short)f2bf(v);
    }
    *(short8v*)&CWf[(size_t)idx * 8] = t;
}

__global__ __launch_bounds__(256) void prep_ef(const float* __restrict__ emb,
                                               unsigned short* __restrict__ Ef) {
    int idx = blockIdx.x * 256 + threadIdx.x;  // [0, 3584): (ks, nf, lane)
    if (idx >= 7 * 8 * 64) return;
    int ks = idx >> 9, nf = (idx >> 6) & 7, lane = idx & 63;
    int j0 = ks * 32 + 8 * (lane >> 4);
    int w = nf * 16 + (lane & 15);
    short8v t;
#pragma unroll
    for (int j8 = 0; j8 < 8; j8++) {
        int j = j0 + j8;
        float v = (j < 208 && w < 121) ? emb[(size_t)(j >> 3) * 128 + w + (j & 7)] : 0.f;
        t[j8] = (short)f2bf(v);
    }
    *(short8v*)&Ef[(size_t)idx * 8] = t;
}

__global__ __launch_bounds__(256) void conv_mfma(const int* __restrict__ target,
                                                 const unsigned short* __restrict__ CWf,
                                                 const unsigned short* __restrict__ Ef,
                                                 const float* __restrict__ convb,
                                                 float* __restrict__ c) {
    __shared__ int tg[1024];
    __shared__ unsigned short A_lds[32 * 256];  // 16 KB
    int n = blockIdx.x;
    int tid = threadIdx.x, lane = tid & 63, wid = tid >> 6;
    int hi = lane >> 4, l15 = lane & 15;
    for (int i = tid; i < 1024; i += 256) tg[i] = (i < 1000) ? target[n * 1000 + i] : -1;
    __syncthreads();

    // phase A: A = onehot @ CW; wave owns 4 of 16 col-frags
    f32x4 acc[2][4];
#pragma unroll
    for (int mf = 0; mf < 2; mf++)
#pragma unroll
        for (int nf = 0; nf < 4; nf++) acc[mf][nf] = (f32x4){0.f, 0.f, 0.f, 0.f};
    int r0 = l15, r1 = l15 + 16;
    for (int ks = 0; ks < 32; ks++) {
        int kk = ks * 32 + 8 * hi;
        i32x4 ta = *(const i32x4*)&tg[kk];
        i32x4 tb = *(const i32x4*)&tg[kk + 4];
        short8v a0, a1;
        a0[0] = (ta.x == r0) ? (short)0x3F80 : (short)0;
        a0[1] = (ta.y == r0) ? (short)0x3F80 : (short)0;
        a0[2] = (ta.z == r0) ? (short)0x3F80 : (short)0;
        a0[3] = (ta.w == r0) ? (short)0x3F80 : (short)0;
        a0[4] = (tb.x == r0) ? (short)0x3F80 : (short)0;
        a0[5] = (tb.y == r0) ? (short)0x3F80 : (short)0;
        a0[6] = (tb.z == r0) ? (short)0x3F80 : (short)0;
        a0[7] = (tb.w == r0) ? (short)0x3F80 : (short)0;
        a1[0] = (ta.x == r1) ? (short)0x3F80 : (short)0;
        a1[1] = (ta.y == r1) ? (short)0x3F80 : (short)0;
        a1[2] = (ta.z == r1) ? (short)0x3F80 : (short)0;
        a1[3] = (ta.w == r1) ? (short)0x3F80 : (short)0;
        a1[4] = (tb.x == r1) ? (short)0x3F80 : (short)0;
        a1[5] = (tb.y == r1) ? (short)0x3F80 : (short)0;
        a1[6] = (tb.z == r1) ? (short)0x3F80 : (short)0;
        a1[7] = (tb.w == r1) ? (short)0x3F80 : (short)0;
#pragma unroll
        for (int nf = 0; nf < 4; nf++) {
            short8v b = *(const short8v*)&CWf[((size_t)(ks * 16 + wid * 4 + nf) * 64 + lane) * 8];
            acc[0][nf] = __builtin_amdgcn_mfma_f32_16x16x32_bf16(a0, b, acc[0][nf], 0, 0, 0);
            acc[1][nf] = __builtin_amdgcn_mfma_f32_16x16x32_bf16(a1, b, acc[1][nf], 0, 0, 0);
        }
    }
#pragma unroll
    for (int mf = 0; mf < 2; mf++)
#pragma unroll
        for (int nf = 0; nf < 4; nf++) {
            int col = (wid * 4 + nf) * 16 + l15;
#pragma unroll
            for (int r = 0; r < 4; r++) {
                int row = 16 * mf + 4 * hi + r;
                A_lds[row * 256 + col] = f2bf(acc[mf][nf][r]);
            }
        }
    __syncthreads();

    // phase B: c = A'' @ E; wave owns 2 of 8 col-frags (w range)
    f32x4 acc2[2][2];
#pragma unroll
    for (int mf = 0; mf < 2; mf++)
#pragma unroll
        for (int nf = 0; nf < 2; nf++) acc2[mf][nf] = (f32x4){0.f, 0.f, 0.f, 0.f};
#pragma unroll
    for (int ks = 0; ks < 7; ks++) {
        int j0 = ks * 32 + 8 * hi;
        int t = j0 >> 3;
        short8v a0 = *(const short8v*)&A_lds[t * 256 + l15 * 8];
        short8v a1 = *(const short8v*)&A_lds[t * 256 + (l15 + 16) * 8];
#pragma unroll
        for (int nf = 0; nf < 2; nf++) {
            short8v b = *(const short8v*)&Ef[((size_t)(ks * 8 + wid * 2 + nf) * 64 + lane) * 8];
            acc2[0][nf] = __builtin_amdgcn_mfma_f32_16x16x32_bf16(a0, b, acc2[0][nf], 0, 0, 0);
            acc2[1][nf] = __builtin_amdgcn_mfma_f32_16x16x32_bf16(a1, b, acc2[1][nf], 0, 0, 0);
        }
    }
#pragma unroll
    for (int mf = 0; mf < 2; mf++)
#pragma unroll
        for (int nf = 0; nf < 2; nf++) {
            int w = (wid * 2 + nf) * 16 + l15;
            if (w < 121) {
#pragma unroll
                for (int r = 0; r < 4; r++) {
                    int o = 16 * mf + 4 * hi + r;
                    c[(size_t)n * 3872 + o * 121 + w] = acc2[mf][nf][r] + convb[o];
                }
            }
        }
}

// ---------------- final N=1 matvec (relu on load) ----------------

__global__ __launch_bounds__(256) void rowdot(const float* __restrict__ f2,
                                              const float* __restrict__ Wo,
                                              const float* __restrict__ bo,
                                              float* __restrict__ out, int M, int K) {
    int row = blockIdx.x * 4 + (threadIdx.x >> 6);
    int lane = threadIdx.x & 63;
    if (row >= M) return;
    float acc = 0.f;
    for (int k = lane; k < K; k += 64) acc += fmaxf(f2[(size_t)row * K + k], 0.f) * Wo[k];
    for (int off = 32; off; off >>= 1) acc += __shfl_down(acc, off);
    if (lane == 0) out[row] = acc + bo[0];
}

// ---------------- launch ----------------

extern "C" void kernel_launch(void* const* d_in, const int* in_sizes, int n_in, void* d_out,
                              int out_size, void* d_ws, size_t ws_size, hipStream_t stream) {
    const float* x = (const float*)d_in[0];
    const int* ei = (const int*)d_in[1];
    const int* batch = (const int*)d_in[2];
    const int* target = (const int*)d_in[3];
    const float* W1 = (const float*)d_in[4];
    const float* b1 = (const float*)d_in[5];
    const float* W2 = (const float*)d_in[6];
    const float* b2 = (const float*)d_in[7];
    const float* W3 = (const float*)d_in[8];
    const float* b3 = (const float*)d_in[9];
    const float* Wg1 = (const float*)d_in[10];
    const float* bg1 = (const float*)d_in[11];
    const float* Wg2 = (const float*)d_in[12];
    const float* bg2 = (const float*)d_in[13];
    const float* emb = (const float*)d_in[14];
    const float* convw = (const float*)d_in[15];
    const float* convb = (const float*)d_in[16];
    const float* Wxt = (const float*)d_in[17];
    const float* bxt = (const float*)d_in[18];
    const float* Wf1 = (const float*)d_in[19];
    const float* bf1 = (const float*)d_in[20];
    const float* Wf2 = (const float*)d_in[21];
    const float* bf2 = (const float*)d_in[22];
    const float* Wo = (const float*)d_in[23];
    const float* bo = (const float*)d_in[24];
    float* out = (float*)d_out;

    const int N = N_NODES, E = N_EDGES;
    const int NB = (N + 511) / 512;

    char* ws = (char*)d_ws;
    size_t off = 0;
    auto alloc = [&](size_t bytes) -> char* {
        char* p = ws + off;
        off = (off + bytes + 255) & ~(size_t)255;
        return p;
    };
    int* cnt = (int*)alloc((size_t)N * 2 * 4);  // cnt + cur, one memset
    int* cur = cnt + N;
    int* rowptr = (int*)alloc((size_t)(N + 1) * 4);
    int* bsum = (int*)alloc(512 * 4);
    int* col = (int*)alloc((size_t)E * 4);
    float* dinv = (float*)alloc((size_t)N * 4);
    int* gstart = (int*)alloc((N_GRAPHS + 1) * 4);
    float* g3 = (float*)alloc((size_t)N_GRAPHS * 312 * 4);
    float* gg = (float*)alloc((size_t)N_GRAPHS * 1024 * 4);
    float* cbuf = (float*)alloc((size_t)N_GRAPHS * 3872 * 4);
    float* xc = (float*)alloc((size_t)N_GRAPHS * 256 * 4);
    float* f1 = (float*)alloc((size_t)N_GRAPHS * 1024 * 4);
    float* f2 = (float*)alloc((size_t)N_GRAPHS * 512 * 4);
    unsigned short* CWf = (unsigned short*)alloc((size_t)32768 * 8 * 2);  // 512 KB
    unsigned short* Ef = (unsigned short*)alloc((size_t)3584 * 8 * 2);    // 56 KB
    unsigned short* W1f = (unsigned short*)alloc((size_t)5 * 3 * 64 * 8 * 2);
    unsigned short* W2f = (unsigned short*)alloc((size_t)10 * 3 * 64 * 8 * 2);
    unsigned short* W3f = (unsigned short*)alloc((size_t)20 * 5 * 64 * 8 * 2);
    unsigned short* U = (unsigned short*)alloc((size_t)N * 160 * 2 + 512);
    unsigned short* P160 = (unsigned short*)alloc((size_t)N * 160 * 2 + 512);
    unsigned short* H1 = U + (size_t)N * 80;  // [N,80] second half of U

    const int* srcp = ei;
    const int* dstp = ei + E;

    // CSR + norm
    hipMemsetAsync(cnt, 0, (size_t)N * 2 * 4, stream);
    count_edges<<<(E + 255) / 256, 256, 0, stream>>>(dstp, E, cnt);
    block_reduce<<<NB, 512, 0, stream>>>(cnt, N, bsum);
    scan_bsums<<<1, 512, 0, stream>>>(bsum, NB);
    block_scan_write<<<NB, 512, 0, stream>>>(cnt, bsum, N, rowptr);
    fill_csr<<<(E + 255) / 256, 256, 0, stream>>>(srcp, dstp, E, rowptr, cur, col);
    compute_dinv<<<(N + 255) / 256, 256, 0, stream>>>(rowptr, N, dinv);
    graph_bounds<<<(N_GRAPHS + 1 + 63) / 64, 64, 0, stream>>>(batch, N, N_GRAPHS, gstart);

    // bias-init split-K outputs (one kernel)
    init_bias_all<<<(N_GRAPHS * 2816 + 255) / 256, 256, 0, stream>>>(gg, bg1, xc, bg2, bxt, f1,
                                                                     bf1, f2, bf2);
    // operand prep (fragment-ordered bf16 weights)
    prep_cwf<<<128, 256, 0, stream>>>(convw, CWf);
    prep_ef<<<14, 256, 0, stream>>>(emb, Ef);
    prep_wf<78, 78, 3, 5><<<4, 256, 0, stream>>>(W1, W1f);
    prep_wf<78, 156, 3, 10><<<8, 256, 0, stream>>>(W2, W2f);
    prep_wf<156, 312, 5, 20><<<25, 256, 0, stream>>>(W3, W3f);

    const int MB = (N + 127) / 128;  // 1563

    // layer 1: XS = x*dinv (P160); A1 = aggsum(XS) (U80); h1' = relu(A1@W1+b1)*dinv (H1)
    scale_x<<<(N * 40 + 255) / 256, 256, 0, stream>>>(x, dinv, P160);
    agg_sum<80, 10, 25><<<(N + 24) / 25, 256, 0, stream>>>(P160, dinv, rowptr, col, U);
    gemm_mfma_node<78, 80, 80, 5, 3><<<MB, 256, 0, stream>>>(U, W1f, b1, dinv, H1, N);
    // layer 2: A2 = aggsum(h1') (P160[:,:80]); h2' = relu(A2@W2+b2)*dinv (U as [N,160])
    agg_sum<80, 10, 25><<<(N + 24) / 25, 256, 0, stream>>>(H1, dinv, rowptr, col, P160);
    gemm_mfma_node<156, 80, 160, 10, 3><<<MB, 256, 0, stream>>>(P160, W2f, b2, dinv, U, N);
    // layer 3: A3 = aggsum(h2') (P160 [N,160]); fused GEMM + per-graph segment max
    agg_sum<160, 20, 12><<<(N + 11) / 12, 256, 0, stream>>>(U, dinv, rowptr, col, P160);
    seg_gemm_max<<<5 * N_GRAPHS, 256, 0, stream>>>(P160, W3f, b3, gstart, g3);

    // graph head
    gemm_splitk<0><<<dim3(16, 32, 2), 256, 0, stream>>>(g3, Wg1, gg, 512, 1024, 312, 1024, 160);
    gemm_splitk<1><<<dim3(2, 32, 8), 256, 0, stream>>>(gg, Wg2, xc, 512, 128, 1024, 256, 128);

    // conv head (MFMA)
    conv_mfma<<<N_GRAPHS, 256, 0, stream>>>(target, CWf, Ef, convb, cbuf);
    gemm_splitk<0><<<dim3(2, 32, 16), 256, 0, stream>>>(cbuf, Wxt, xc + 128, 512, 128, 3872, 256, 256);

    // final MLP
    gemm_splitk<0><<<dim3(16, 32, 2), 256, 0, stream>>>(xc, Wf1, f1, 512, 1024, 256, 1024, 128);
    gemm_splitk<1><<<dim3(8, 32, 8), 256, 0, stream>>>(f1, Wf2, f2, 512, 512, 1024, 512, 128);
    rowdot<<<(N_GRAPHS + 3) / 4, 256, 0, stream>>>(f2, Wo, bo, out, N_GRAPHS, 512);
}

// Round 10
// 664.056 us; speedup vs baseline: 2.1084x; 1.0403x over previous
//
#include <hip/hip_runtime.h>
#include <hip/hip_bf16.h>

#define N_NODES 200000
#define N_EDGES 800000
#define N_GRAPHS 512

typedef __attribute__((ext_vector_type(8))) short short8v;
typedef __attribute__((ext_vector_type(4))) float f32x4;
typedef __attribute__((ext_vector_type(2))) float f32x2;
typedef __attribute__((ext_vector_type(2))) unsigned int u32x2;
typedef __attribute__((ext_vector_type(4))) unsigned int u32x4;
typedef __attribute__((ext_vector_type(4))) int i32x4;

__device__ inline float bf2f(unsigned int u) {
    union { unsigned int i; float f; } c;
    c.i = u << 16;
    return c.f;
}
__device__ inline unsigned short f2bf(float f) {
    union { __hip_bfloat16 h; unsigned short u; } c;
    c.h = __float2bfloat16(f);
    return c.u;
}

// ---------------- CSR build ----------------

__global__ __launch_bounds__(256) void count_edges(const int* __restrict__ dst, int E,
                                                   int* __restrict__ cnt) {
    int e = blockIdx.x * 256 + threadIdx.x;
    if (e < E) atomicAdd(&cnt[dst[e]], 1);
}

__global__ __launch_bounds__(512) void block_reduce(const int* __restrict__ in, int n,
                                                    int* __restrict__ bsum) {
    __shared__ int s[512];
    int i = blockIdx.x * 512 + threadIdx.x;
    s[threadIdx.x] = (i < n) ? in[i] : 0;
    __syncthreads();
    for (int off = 256; off; off >>= 1) {
        if (threadIdx.x < off) s[threadIdx.x] += s[threadIdx.x + off];
        __syncthreads();
    }
    if (threadIdx.x == 0) bsum[blockIdx.x] = s[0];
}

// block 0: exclusive scan of bsum; block 1: graph boundary binary search
__global__ __launch_bounds__(512) void scan_and_bounds(int* bsum, int nb,
                                                       const int* __restrict__ batch, int n,
                                                       int ng, int* __restrict__ gstart) {
    if (blockIdx.x == 1) {
        int b = threadIdx.x;
        if (b == 0) gstart[ng] = n;
        if (b < ng) {
            int lo = 0, hi = n;
            while (lo < hi) {
                int mid = (lo + hi) >> 1;
                if (batch[mid] < b) lo = mid + 1; else hi = mid;
            }
            gstart[b] = lo;
        }
        return;
    }
    __shared__ int buf[2][512];
    int t = threadIdx.x;
    int v = (t < nb) ? bsum[t] : 0;
    buf[0][t] = v;
    __syncthreads();
    int src = 0;
    for (int off = 1; off < 512; off <<= 1) {
        int x = buf[src][t];
        if (t >= off) x += buf[src][t - off];
        buf[src ^ 1][t] = x;
        src ^= 1;
        __syncthreads();
    }
    if (t < nb) bsum[t] = buf[src][t] - v;  // exclusive
}

// also emits dinv[i] = rsqrt(cnt[i]+1)
__global__ __launch_bounds__(512) void block_scan_write(const int* __restrict__ cnt,
                                                        const int* __restrict__ bsum, int n,
                                                        int* __restrict__ rowptr,
                                                        float* __restrict__ dinv) {
    __shared__ int buf[2][512];
    int t = threadIdx.x;
    int i = blockIdx.x * 512 + t;
    int v = (i < n) ? cnt[i] : 0;
    buf[0][t] = v;
    __syncthreads();
    int src = 0;
    for (int off = 1; off < 512; off <<= 1) {
        int x = buf[src][t];
        if (t >= off) x += buf[src][t - off];
        buf[src ^ 1][t] = x;
        src ^= 1;
        __syncthreads();
    }
    int incl = buf[src][t];
    int base = bsum[blockIdx.x];
    if (i < n) {
        rowptr[i] = base + incl - v;
        dinv[i] = rsqrtf((float)(v + 1));
    }
    if (i == n - 1) rowptr[n] = base + incl;
}

__global__ __launch_bounds__(256) void fill_csr(const int* __restrict__ src,
                                                const int* __restrict__ dst, int E,
                                                const int* __restrict__ rowptr,
                                                int* __restrict__ cur, int* __restrict__ col) {
    int e = blockIdx.x * 256 + threadIdx.x;
    if (e < E) {
        int d = dst[e];
        int p = atomicAdd(&cur[d], 1);
        col[rowptr[d] + p] = src[e];
    }
}

// ---- xs[v] = x[v]*dinv[v] -> bf16 [N][80] (cols 78,79 = 0) ----

__global__ __launch_bounds__(256) void scale_x(const float* __restrict__ x,
                                               const float* __restrict__ dinv,
                                               unsigned short* __restrict__ XS) {
    int idx = blockIdx.x * 256 + threadIdx.x;
    int v = idx / 40, c = idx % 40;
    if (v >= N_NODES) return;
    if (c == 39) {
        *(unsigned int*)(XS + (size_t)v * 80 + 78) = 0u;
        return;
    }
    float dv = dinv[v];
    f32x2 xv = *(const f32x2*)(x + (size_t)v * 78 + c * 2);
    unsigned int pack = ((unsigned int)f2bf(xv.y * dv) << 16) | f2bf(xv.x * dv);
    *(unsigned int*)(XS + (size_t)v * 80 + c * 2) = pack;
}

// ---- aggregation on pre-scaled features: out[v] = dinv[v]*(sum_{u in N(v)} X[u] + X[v]) ----
// edge loop unrolled x2: two independent gather/accumulate chains for MLP.

template <int LD, int NCH, int NPB>
__global__ __launch_bounds__(256) void agg_sum(const unsigned short* __restrict__ X,
                                               const float* __restrict__ dinv,
                                               const int* __restrict__ rowptr,
                                               const int* __restrict__ col,
                                               unsigned short* __restrict__ out) {
    int tid = threadIdx.x;
    if (tid >= NPB * NCH) return;
    int v = blockIdx.x * NPB + tid / NCH;
    int c = tid % NCH;
    if (v >= N_NODES) return;
    const unsigned short* Xc = X + c * 8;
    u32x4 xv = *(const u32x4*)(Xc + (size_t)v * LD);
    float a0 = bf2f(xv.x & 0xffffu), a1 = bf2f(xv.x >> 16);
    float a2 = bf2f(xv.y & 0xffffu), a3 = bf2f(xv.y >> 16);
    float a4 = bf2f(xv.z & 0xffffu), a5 = bf2f(xv.z >> 16);
    float a6 = bf2f(xv.w & 0xffffu), a7 = bf2f(xv.w >> 16);
    float b0 = 0.f, b1 = 0.f, b2 = 0.f, b3 = 0.f, b4 = 0.f, b5 = 0.f, b6 = 0.f, b7 = 0.f;
    int r0 = rowptr[v], r1 = rowptr[v + 1];
    int e = r0;
    for (; e + 1 < r1; e += 2) {
        int u0 = col[e], u1 = col[e + 1];
        u32x4 p = *(const u32x4*)(Xc + (size_t)u0 * LD);
        u32x4 q = *(const u32x4*)(Xc + (size_t)u1 * LD);
        a0 += bf2f(p.x & 0xffffu);
        a1 += bf2f(p.x >> 16);
        a2 += bf2f(p.y & 0xffffu);
        a3 += bf2f(p.y >> 16);
        a4 += bf2f(p.z & 0xffffu);
        a5 += bf2f(p.z >> 16);
        a6 += bf2f(p.w & 0xffffu);
        a7 += bf2f(p.w >> 16);
        b0 += bf2f(q.x & 0xffffu);
        b1 += bf2f(q.x >> 16);
        b2 += bf2f(q.y & 0xffffu);
        b3 += bf2f(q.y >> 16);
        b4 += bf2f(q.z & 0xffffu);
        b5 += bf2f(q.z >> 16);
        b6 += bf2f(q.w & 0xffffu);
        b7 += bf2f(q.w >> 16);
    }
    if (e < r1) {
        int u = col[e];
        u32x4 p = *(const u32x4*)(Xc + (size_t)u * LD);
        a0 += bf2f(p.x & 0xffffu);
        a1 += bf2f(p.x >> 16);
        a2 += bf2f(p.y & 0xffffu);
        a3 += bf2f(p.y >> 16);
        a4 += bf2f(p.z & 0xffffu);
        a5 += bf2f(p.z >> 16);
        a6 += bf2f(p.w & 0xffffu);
        a7 += bf2f(p.w >> 16);
    }
    float dv = dinv[v];
    u32x4 o;
    o.x = ((unsigned int)f2bf((a1 + b1) * dv) << 16) | f2bf((a0 + b0) * dv);
    o.y = ((unsigned int)f2bf((a3 + b3) * dv) << 16) | f2bf((a2 + b2) * dv);
    o.z = ((unsigned int)f2bf((a5 + b5) * dv) << 16) | f2bf((a4 + b4) * dv);
    o.w = ((unsigned int)f2bf((a7 + b7) * dv) << 16) | f2bf((a6 + b6) * dv);
    *(u32x4*)(out + (size_t)v * LD + c * 8) = o;
}

// ---- merged one-time setup: init_bias_all + prep_cwf + prep_ef + prep_wf x3 ----

__device__ inline void prep_wf_body(const float* __restrict__ W, unsigned short* __restrict__ Wf,
                                    int idx, int KREAL, int NREAL, int KS, int NF) {
    if (idx >= NF * KS * 64) return;
    int lane = idx & 63, ks = (idx >> 6) % KS, nf = idx / (64 * KS);
    int k0 = ks * 32 + 8 * (lane >> 4);
    int cc = nf * 16 + (lane & 15);
    short8v t;
#pragma unroll
    for (int j = 0; j < 8; j++) {
        int k = k0 + j;
        float w = (k < KREAL && cc < NREAL) ? W[(size_t)k * NREAL + cc] : 0.f;
        t[j] = (short)f2bf(w);
    }
    *(short8v*)&Wf[(size_t)idx * 8] = t;
}

__global__ __launch_bounds__(256) void setup_misc(
    float* __restrict__ gg, const float* __restrict__ bg1, float* __restrict__ xc,
    const float* __restrict__ bg2, const float* __restrict__ bxt, float* __restrict__ f1,
    const float* __restrict__ bf1, float* __restrict__ f2, const float* __restrict__ bf2,
    const float* __restrict__ convw, unsigned short* __restrict__ CWf,
    const float* __restrict__ emb, unsigned short* __restrict__ Ef,
    const float* __restrict__ W1, unsigned short* __restrict__ W1f,
    const float* __restrict__ W2, unsigned short* __restrict__ W2f,
    const float* __restrict__ W3, unsigned short* __restrict__ W3f) {
    int b = blockIdx.x;
    int tid = threadIdx.x;
    if (b < 5632) {  // init_bias_all: 512*2816 elems
        int idx = b * 256 + tid;
        int row = idx / 2816, c = idx % 2816;
        if (row >= N_GRAPHS) return;
        if (c < 1024) gg[(size_t)row * 1024 + c] = bg1[c];
        else if (c < 1280) {
            int j = c - 1024;
            xc[(size_t)row * 256 + j] = (j < 128) ? bg2[j] : bxt[j - 128];
        } else if (c < 2304)
            f1[(size_t)row * 1024 + (c - 1280)] = bf1[c - 1280];
        else
            f2[(size_t)row * 512 + (c - 2304)] = bf2[c - 2304];
        return;
    }
    b -= 5632;
    if (b < 128) {  // prep_cwf
        int idx = b * 256 + tid;
        int ks = idx >> 10, nf = (idx >> 6) & 15, lane = idx & 63;
        int k0 = ks * 32 + 8 * (lane >> 4);
        int c = nf * 16 + (lane & 15);
        int o = c >> 3, kk = c & 7;
        short8v t;
#pragma unroll
        for (int j = 0; j < 8; j++) {
            int k = k0 + j;
            float v = (k < 1000) ? convw[(size_t)o * 8000 + k * 8 + kk] : 0.f;
            t[j] = (short)f2bf(v);
        }
        *(short8v*)&CWf[(size_t)idx * 8] = t;
        return;
    }
    b -= 128;
    if (b < 14) {  // prep_ef
        int idx = b * 256 + tid;
        if (idx >= 7 * 8 * 64) return;
        int ks = idx >> 9, nf = (idx >> 6) & 7, lane = idx & 63;
        int j0 = ks * 32 + 8 * (lane >> 4);
        int w = nf * 16 + (lane & 15);
        short8v t;
#pragma unroll
        for (int j8 = 0; j8 < 8; j8++) {
            int j = j0 + j8;
            float v = (j < 208 && w < 121) ? emb[(size_t)(j >> 3) * 128 + w + (j & 7)] : 0.f;
            t[j8] = (short)f2bf(v);
        }
        *(short8v*)&Ef[(size_t)idx * 8] = t;
        return;
    }
    b -= 14;
    if (b < 4) { prep_wf_body(W1, W1f, b * 256 + tid, 78, 78, 3, 5); return; }
    b -= 4;
    if (b < 8) { prep_wf_body(W2, W2f, b * 256 + tid, 78, 156, 3, 10); return; }
    b -= 8;
    prep_wf_body(W3, W3f, b * 256 + tid, 156, 312, 5, 20);
}

// ------- MFMA node GEMM: Cout = relu(A @ W + bias) * dinv[row], bf16 in/out -------

template <int NREAL, int LDA, int LDC, int NF, int KS>
__global__ __launch_bounds__(256) void gemm_mfma_node(const unsigned short* __restrict__ A,
                                                      const unsigned short* __restrict__ Wf,
                                                      const float* __restrict__ bias,
                                                      const float* __restrict__ dinv,
                                                      unsigned short* __restrict__ Cout, int M) {
    __shared__ unsigned short Bs[NF * KS * 64 * 8];
    int tid = threadIdx.x;
    for (int idx = tid; idx < NF * KS * 64; idx += 256)
        *(short8v*)&Bs[idx * 8] = *(const short8v*)&Wf[(size_t)idx * 8];
    __syncthreads();

    int lane = tid & 63, wid = tid >> 6;
    int m0 = blockIdx.x * 128 + wid * 32;
    float biasr[NF];
#pragma unroll
    for (int nf = 0; nf < NF; nf++) {
        int cc = nf * 16 + (lane & 15);
        biasr[nf] = (cc < NREAL) ? bias[cc] : 0.f;
    }
    f32x4 acc[2][NF];
#pragma unroll
    for (int mf = 0; mf < 2; mf++)
#pragma unroll
        for (int nf = 0; nf < NF; nf++) acc[mf][nf] = (f32x4){0.f, 0.f, 0.f, 0.f};

    int ra = min(m0 + (lane & 15), M - 1);
    int rb = min(m0 + 16 + (lane & 15), M - 1);
#pragma unroll
    for (int ks = 0; ks < KS; ks++) {
        int koff = ks * 32 + 8 * (lane >> 4);
        short8v a0 = *(const short8v*)(A + (size_t)ra * LDA + koff);
        short8v a1 = *(const short8v*)(A + (size_t)rb * LDA + koff);
#pragma unroll
        for (int nf = 0; nf < NF; nf++) {
            short8v b = *(const short8v*)&Bs[((nf * KS + ks) * 64 + lane) * 8];
            acc[0][nf] = __builtin_amdgcn_mfma_f32_16x16x32_bf16(a0, b, acc[0][nf], 0, 0, 0);
            acc[1][nf] = __builtin_amdgcn_mfma_f32_16x16x32_bf16(a1, b, acc[1][nf], 0, 0, 0);
        }
    }
    float dr[2][4];
#pragma unroll
    for (int mf = 0; mf < 2; mf++)
#pragma unroll
        for (int r = 0; r < 4; r++) {
            int row = m0 + mf * 16 + 4 * (lane >> 4) + r;
            dr[mf][r] = dinv[min(row, M - 1)];
        }
#pragma unroll
    for (int mf = 0; mf < 2; mf++) {
#pragma unroll
        for (int nf = 0; nf < NF; nf++) {
            int cc = nf * 16 + (lane & 15);
#pragma unroll
            for (int r = 0; r < 4; r++) {
                int row = m0 + mf * 16 + 4 * (lane >> 4) + r;
                float v = fmaxf(acc[mf][nf][r] + biasr[nf], 0.f) * dr[mf][r];
                unsigned short o = (cc < NREAL) ? f2bf(v) : (unsigned short)0;
                if (row < M) Cout[(size_t)row * LDC + cc] = o;
            }
        }
    }
}

// ------- layer-3 GEMM fused with per-graph segment-max ----
// 1D grid 2560: bx = id>>9 (col-block of 64), g = id&511 (graph). All 5 col-blocks of a
// graph share XCD (512 % 8 == 0) -> A rows L2-hit after first touch.

__global__ __launch_bounds__(256) void seg_gemm_max(const unsigned short* __restrict__ A,
                                                    const unsigned short* __restrict__ Wf3,
                                                    const float* __restrict__ b3,
                                                    const int* __restrict__ gstart,
                                                    float* __restrict__ g3) {
    __shared__ unsigned short Bs[4 * 5 * 64 * 8];  // 20 KB
    __shared__ float wmax[4][64];
    int g = blockIdx.x & 511;
    int bx = blockIdx.x >> 9;
    int c0 = bx * 64;
    int r0 = gstart[g], r1 = gstart[g + 1];
    int tid = threadIdx.x, lane = tid & 63, wid = tid >> 6;

    const unsigned short* src = Wf3 + (size_t)bx * 4 * 5 * 64 * 8;
    for (int idx = tid; idx < 1280; idx += 256)
        *(short8v*)&Bs[idx * 8] = *(const short8v*)&src[(size_t)idx * 8];
    __syncthreads();

    float biasr[4], cmax[4];
#pragma unroll
    for (int nf = 0; nf < 4; nf++) {
        int cc = c0 + nf * 16 + (lane & 15);
        biasr[nf] = (cc < 312) ? b3[cc] : 0.f;
        cmax[nf] = 0.f;
    }

    for (int mt = r0 + wid * 32; mt < r1; mt += 128) {
        f32x4 acc[2][4];
#pragma unroll
        for (int mf = 0; mf < 2; mf++)
#pragma unroll
            for (int nf = 0; nf < 4; nf++) acc[mf][nf] = (f32x4){0.f, 0.f, 0.f, 0.f};
        int ra = min(mt + (lane & 15), N_NODES - 1);
        int rb = min(mt + 16 + (lane & 15), N_NODES - 1);
#pragma unroll
        for (int ks = 0; ks < 5; ks++) {
            int koff = ks * 32 + 8 * (lane >> 4);
            short8v a0 = *(const short8v*)(A + (size_t)ra * 160 + koff);
            short8v a1 = *(const short8v*)(A + (size_t)rb * 160 + koff);
#pragma unroll
            for (int nf = 0; nf < 4; nf++) {
                short8v b = *(const short8v*)&Bs[((nf * 5 + ks) * 64 + lane) * 8];
                acc[0][nf] = __builtin_amdgcn_mfma_f32_16x16x32_bf16(a0, b, acc[0][nf], 0, 0, 0);
                acc[1][nf] = __builtin_amdgcn_mfma_f32_16x16x32_bf16(a1, b, acc[1][nf], 0, 0, 0);
            }
        }
#pragma unroll
        for (int mf = 0; mf < 2; mf++) {
#pragma unroll
            for (int nf = 0; nf < 4; nf++) {
#pragma unroll
                for (int r = 0; r < 4; r++) {
                    int row = mt + mf * 16 + 4 * (lane >> 4) + r;
                    float v = fmaxf(acc[mf][nf][r] + biasr[nf], 0.f);
                    if (row < r1) cmax[nf] = fmaxf(cmax[nf], v);
                }
            }
        }
    }
#pragma unroll
    for (int nf = 0; nf < 4; nf++) {
        float m = cmax[nf];
        m = fmaxf(m, __shfl_xor(m, 16));
        m = fmaxf(m, __shfl_xor(m, 32));
        if (lane < 16) wmax[wid][nf * 16 + lane] = m;
    }
    __syncthreads();
    if (tid < 64) {
        float m = fmaxf(fmaxf(wmax[0][tid], wmax[1][tid]), fmaxf(wmax[2][tid], wmax[3][tid]));
        int cc = c0 + tid;
        if (cc < 312) g3[(size_t)g * 312 + cc] = m;
    }
}

// ---------------- head GEMMs: split-K, atomicAdd into bias-initialized C ----------------

template <int RELUA>
__global__ __launch_bounds__(256) void gemm_splitk(const float* __restrict__ A,
                                                   const float* __restrict__ B,
                                                   float* __restrict__ C, int M, int N, int K,
                                                   int ldc, int Kc) {
    __shared__ float As[16][17];
    __shared__ float Bs[16][64];
    int bx = blockIdx.x, by = blockIdx.y, bz = blockIdx.z;
    int tid = threadIdx.x;
    int lane = tid & 63, wy = tid >> 6;
    int n0 = bx * 64, m0 = by * 16;
    int k0 = bz * Kc, k1 = min(K, k0 + Kc);
    float acc[4] = {0.f, 0.f, 0.f, 0.f};
    for (int kt = k0; kt < k1; kt += 16) {
        {
            int r = tid >> 4, kk = tid & 15;
            int gm = m0 + r, gk = kt + kk;
            float v = (gk < k1 && gm < M) ? A[(size_t)gm * K + gk] : 0.f;
            if (RELUA) v = fmaxf(v, 0.f);
            As[kk][r] = v;
        }
#pragma unroll
        for (int l = 0; l < 4; l++) {
            int kk = wy + l * 4;
            int gk = kt + kk, gn = n0 + lane;
            Bs[kk][lane] = (gk < k1 && gn < N) ? B[(size_t)gk * N + gn] : 0.f;
        }
        __syncthreads();
#pragma unroll
        for (int kk = 0; kk < 16; kk++) {
            float b = Bs[kk][lane];
#pragma unroll
            for (int r = 0; r < 4; r++) acc[r] += As[kk][wy * 4 + r] * b;
        }
        __syncthreads();
    }
    int gn = n0 + lane;
    if (gn < N) {
#pragma unroll
        for (int r = 0; r < 4; r++) {
            int gm = m0 + wy * 4 + r;
            if (gm < M) atomicAdd(&C[(size_t)gm * ldc + gn], acc[r]);
        }
    }
}

// ---------------- conv head via MFMA ----------------

__global__ __launch_bounds__(256) void conv_mfma(const int* __restrict__ target,
                                                 const unsigned short* __restrict__ CWf,
                                                 const unsigned short* __restrict__ Ef,
                                                 const float* __restrict__ convb,
                                                 float* __restrict__ c) {
    __shared__ int tg[1024];
    __shared__ unsigned short A_lds[32 * 256];  // 16 KB
    int n = blockIdx.x;
    int tid = threadIdx.x, lane = tid & 63, wid = tid >> 6;
    int hi = lane >> 4, l15 = lane & 15;
    for (int i = tid; i < 1024; i += 256) tg[i] = (i < 1000) ? target[n * 1000 + i] : -1;
    __syncthreads();

    // phase A: A = onehot @ CW; wave owns 4 of 16 col-frags
    f32x4 acc[2][4];
#pragma unroll
    for (int mf = 0; mf < 2; mf++)
#pragma unroll
        for (int nf = 0; nf < 4; nf++) acc[mf][nf] = (f32x4){0.f, 0.f, 0.f, 0.f};
    int r0 = l15, r1 = l15 + 16;
    for (int ks = 0; ks < 32; ks++) {
        int kk = ks * 32 + 8 * hi;
        i32x4 ta = *(const i32x4*)&tg[kk];
        i32x4 tb = *(const i32x4*)&tg[kk + 4];
        short8v a0, a1;
        a0[0] = (ta.x == r0) ? (short)0x3F80 : (short)0;
        a0[1] = (ta.y == r0) ? (short)0x3F80 : (short)0;
        a0[2] = (ta.z == r0) ? (short)0x3F80 : (short)0;
        a0[3] = (ta.w == r0) ? (short)0x3F80 : (short)0;
        a0[4] = (tb.x == r0) ? (short)0x3F80 : (short)0;
        a0[5] = (tb.y == r0) ? (short)0x3F80 : (short)0;
        a0[6] = (tb.z == r0) ? (short)0x3F80 : (short)0;
        a0[7] = (tb.w == r0) ? (short)0x3F80 : (short)0;
        a1[0] = (ta.x == r1) ? (short)0x3F80 : (short)0;
        a1[1] = (ta.y == r1) ? (short)0x3F80 : (short)0;
        a1[2] = (ta.z == r1) ? (short)0x3F80 : (short)0;
        a1[3] = (ta.w == r1) ? (short)0x3F80 : (short)0;
        a1[4] = (tb.x == r1) ? (short)0x3F80 : (short)0;
        a1[5] = (tb.y == r1) ? (short)0x3F80 : (short)0;
        a1[6] = (tb.z == r1) ? (short)0x3F80 : (short)0;
        a1[7] = (tb.w == r1) ? (short)0x3F80 : (short)0;
#pragma unroll
        for (int nf = 0; nf < 4; nf++) {
            short8v b = *(const short8v*)&CWf[((size_t)(ks * 16 + wid * 4 + nf) * 64 + lane) * 8];
            acc[0][nf] = __builtin_amdgcn_mfma_f32_16x16x32_bf16(a0, b, acc[0][nf], 0, 0, 0);
            acc[1][nf] = __builtin_amdgcn_mfma_f32_16x16x32_bf16(a1, b, acc[1][nf], 0, 0, 0);
        }
    }
#pragma unroll
    for (int mf = 0; mf < 2; mf++)
#pragma unroll
        for (int nf = 0; nf < 4; nf++) {
            int col = (wid * 4 + nf) * 16 + l15;
#pragma unroll
            for (int r = 0; r < 4; r++) {
                int row = 16 * mf + 4 * hi + r;
                A_lds[row * 256 + col] = f2bf(acc[mf][nf][r]);
            }
        }
    __syncthreads();

    // phase B: c = A'' @ E; wave owns 2 of 8 col-frags (w range)
    f32x4 acc2[2][2];
#pragma unroll
    for (int mf = 0; mf < 2; mf++)
#pragma unroll
        for (int nf = 0; nf < 2; nf++) acc2[mf][nf] = (f32x4){0.f, 0.f, 0.f, 0.f};
#pragma unroll
    for (int ks = 0; ks < 7; ks++) {
        int j0 = ks * 32 + 8 * hi;
        int t = j0 >> 3;
        short8v a0 = *(const short8v*)&A_lds[t * 256 + l15 * 8];
        short8v a1 = *(const short8v*)&A_lds[t * 256 + (l15 + 16) * 8];
#pragma unroll
        for (int nf = 0; nf < 2; nf++) {
            short8v b = *(const short8v*)&Ef[((size_t)(ks * 8 + wid * 2 + nf) * 64 + lane) * 8];
            acc2[0][nf] = __builtin_amdgcn_mfma_f32_16x16x32_bf16(a0, b, acc2[0][nf], 0, 0, 0);
            acc2[1][nf] = __builtin_amdgcn_mfma_f32_16x16x32_bf16(a1, b, acc2[1][nf], 0, 0, 0);
        }
    }
#pragma unroll
    for (int mf = 0; mf < 2; mf++)
#pragma unroll
        for (int nf = 0; nf < 2; nf++) {
            int w = (wid * 2 + nf) * 16 + l15;
            if (w < 121) {
#pragma unroll
                for (int r = 0; r < 4; r++) {
                    int o = 16 * mf + 4 * hi + r;
                    c[(size_t)n * 3872 + o * 121 + w] = acc2[mf][nf][r] + convb[o];
                }
            }
        }
}

// ---------------- final N=1 matvec (relu on load) ----------------

__global__ __launch_bounds__(256) void rowdot(const float* __restrict__ f2,
                                              const float* __restrict__ Wo,
                                              const float* __restrict__ bo,
                                              float* __restrict__ out, int M, int K) {
    int row = blockIdx.x * 4 + (threadIdx.x >> 6);
    int lane = threadIdx.x & 63;
    if (row >= M) return;
    float acc = 0.f;
    for (int k = lane; k < K; k += 64) acc += fmaxf(f2[(size_t)row * K + k], 0.f) * Wo[k];
    for (int off = 32; off; off >>= 1) acc += __shfl_down(acc, off);
    if (lane == 0) out[row] = acc + bo[0];
}

// ---------------- launch ----------------

extern "C" void kernel_launch(void* const* d_in, const int* in_sizes, int n_in, void* d_out,
                              int out_size, void* d_ws, size_t ws_size, hipStream_t stream) {
    const float* x = (const float*)d_in[0];
    const int* ei = (const int*)d_in[1];
    const int* batch = (const int*)d_in[2];
    const int* target = (const int*)d_in[3];
    const float* W1 = (const float*)d_in[4];
    const float* b1 = (const float*)d_in[5];
    const float* W2 = (const float*)d_in[6];
    const float* b2 = (const float*)d_in[7];
    const float* W3 = (const float*)d_in[8];
    const float* b3 = (const float*)d_in[9];
    const float* Wg1 = (const float*)d_in[10];
    const float* bg1 = (const float*)d_in[11];
    const float* Wg2 = (const float*)d_in[12];
    const float* bg2 = (const float*)d_in[13];
    const float* emb = (const float*)d_in[14];
    const float* convw = (const float*)d_in[15];
    const float* convb = (const float*)d_in[16];
    const float* Wxt = (const float*)d_in[17];
    const float* bxt = (const float*)d_in[18];
    const float* Wf1 = (const float*)d_in[19];
    const float* bf1 = (const float*)d_in[20];
    const float* Wf2 = (const float*)d_in[21];
    const float* bf2 = (const float*)d_in[22];
    const float* Wo = (const float*)d_in[23];
    const float* bo = (const float*)d_in[24];
    float* out = (float*)d_out;

    const int N = N_NODES, E = N_EDGES;
    const int NB = (N + 511) / 512;

    char* ws = (char*)d_ws;
    size_t off = 0;
    auto alloc = [&](size_t bytes) -> char* {
        char* p = ws + off;
        off = (off + bytes + 255) & ~(size_t)255;
        return p;
    };
    int* cnt = (int*)alloc((size_t)N * 2 * 4);  // cnt + cur, one memset
    int* cur = cnt + N;
    int* rowptr = (int*)alloc((size_t)(N + 1) * 4);
    int* bsum = (int*)alloc(512 * 4);
    int* col = (int*)alloc((size_t)E * 4);
    float* dinv = (float*)alloc((size_t)N * 4);
    int* gstart = (int*)alloc((N_GRAPHS + 1) * 4);
    float* g3 = (float*)alloc((size_t)N_GRAPHS * 312 * 4);
    float* gg = (float*)alloc((size_t)N_GRAPHS * 1024 * 4);
    float* cbuf = (float*)alloc((size_t)N_GRAPHS * 3872 * 4);
    float* xc = (float*)alloc((size_t)N_GRAPHS * 256 * 4);
    float* f1 = (float*)alloc((size_t)N_GRAPHS * 1024 * 4);
    float* f2 = (float*)alloc((size_t)N_GRAPHS * 512 * 4);
    unsigned short* CWf = (unsigned short*)alloc((size_t)32768 * 8 * 2);  // 512 KB
    unsigned short* Ef = (unsigned short*)alloc((size_t)3584 * 8 * 2);    // 56 KB
    unsigned short* W1f = (unsigned short*)alloc((size_t)5 * 3 * 64 * 8 * 2);
    unsigned short* W2f = (unsigned short*)alloc((size_t)10 * 3 * 64 * 8 * 2);
    unsigned short* W3f = (unsigned short*)alloc((size_t)20 * 5 * 64 * 8 * 2);
    unsigned short* U = (unsigned short*)alloc((size_t)N * 160 * 2 + 512);
    unsigned short* P160 = (unsigned short*)alloc((size_t)N * 160 * 2 + 512);
    unsigned short* H1 = U + (size_t)N * 80;  // [N,80] second half of U

    const int* srcp = ei;
    const int* dstp = ei + E;

    // CSR + norm (+ graph bounds + dinv folded in)
    hipMemsetAsync(cnt, 0, (size_t)N * 2 * 4, stream);
    count_edges<<<(E + 255) / 256, 256, 0, stream>>>(dstp, E, cnt);
    block_reduce<<<NB, 512, 0, stream>>>(cnt, N, bsum);
    scan_and_bounds<<<2, 512, 0, stream>>>(bsum, NB, batch, N, N_GRAPHS, gstart);
    block_scan_write<<<NB, 512, 0, stream>>>(cnt, bsum, N, rowptr, dinv);
    fill_csr<<<(E + 255) / 256, 256, 0, stream>>>(srcp, dstp, E, rowptr, cur, col);

    // merged one-time setup: bias-init + all operand preps (5811 blocks)
    setup_misc<<<5632 + 128 + 14 + 4 + 8 + 25, 256, 0, stream>>>(
        gg, bg1, xc, bg2, bxt, f1, bf1, f2, bf2, convw, CWf, emb, Ef, W1, W1f, W2, W2f, W3, W3f);

    const int MB = (N + 127) / 128;  // 1563

    // layer 1: XS = x*dinv (P160); A1 = aggsum(XS) (U80); h1' = relu(A1@W1+b1)*dinv (H1)
    scale_x<<<(N * 40 + 255) / 256, 256, 0, stream>>>(x, dinv, P160);
    agg_sum<80, 10, 25><<<(N + 24) / 25, 256, 0, stream>>>(P160, dinv, rowptr, col, U);
    gemm_mfma_node<78, 80, 80, 5, 3><<<MB, 256, 0, stream>>>(U, W1f, b1, dinv, H1, N);
    // layer 2: A2 = aggsum(h1') (P160[:,:80]); h2' = relu(A2@W2+b2)*dinv (U as [N,160])
    agg_sum<80, 10, 25><<<(N + 24) / 25, 256, 0, stream>>>(H1, dinv, rowptr, col, P160);
    gemm_mfma_node<156, 80, 160, 10, 3><<<MB, 256, 0, stream>>>(P160, W2f, b2, dinv, U, N);
    // layer 3: A3 = aggsum(h2') (P160 [N,160]); fused GEMM + per-graph segment max
    agg_sum<160, 20, 12><<<(N + 11) / 12, 256, 0, stream>>>(U, dinv, rowptr, col, P160);
    seg_gemm_max<<<5 * N_GRAPHS, 256, 0, stream>>>(P160, W3f, b3, gstart, g3);

    // graph head
    gemm_splitk<0><<<dim3(16, 32, 2), 256, 0, stream>>>(g3, Wg1, gg, 512, 1024, 312, 1024, 160);
    gemm_splitk<1><<<dim3(2, 32, 8), 256, 0, stream>>>(gg, Wg2, xc, 512, 128, 1024, 256, 128);

    // conv head (MFMA)
    conv_mfma<<<N_GRAPHS, 256, 0, stream>>>(target, CWf, Ef, convb, cbuf);
    gemm_splitk<0><<<dim3(2, 32, 16), 256, 0, stream>>>(cbuf, Wxt, xc + 128, 512, 128, 3872, 256, 256);

    // final MLP
    gemm_splitk<0><<<dim3(16, 32, 2), 256, 0, stream>>>(xc, Wf1, f1, 512, 1024, 256, 1024, 128);
    gemm_splitk<1><<<dim3(8, 32, 8), 256, 0, stream>>>(f1, Wf2, f2, 512, 512, 1024, 512, 128);
    rowdot<<<(N_GRAPHS + 3) / 4, 256, 0, stream>>>(f2, Wo, bo, out, N_GRAPHS, 512);
}

// Round 11
// 602.522 us; speedup vs baseline: 2.3237x; 1.1021x over previous
//
#include <hip/hip_runtime.h>
#include <hip/hip_bf16.h>

#define N_NODES 200000
#define N_EDGES 800000
#define N_GRAPHS 512

typedef __attribute__((ext_vector_type(8))) short short8v;
typedef __attribute__((ext_vector_type(4))) float f32x4;
typedef __attribute__((ext_vector_type(2))) float f32x2;
typedef __attribute__((ext_vector_type(4))) unsigned int u32x4;
typedef __attribute__((ext_vector_type(4))) int i32x4;

__device__ inline float bf2f(unsigned int u) {
    union { unsigned int i; float f; } c;
    c.i = u << 16;
    return c.f;
}
__device__ inline unsigned short f2bf(float f) {
    union { __hip_bfloat16 h; unsigned short u; } c;
    c.h = __float2bfloat16(f);
    return c.u;
}

// ---------------- CSR build ----------------

__global__ __launch_bounds__(256) void count_edges(const int* __restrict__ dst, int E,
                                                   int* __restrict__ cnt) {
    int e = blockIdx.x * 256 + threadIdx.x;
    if (e < E) atomicAdd(&cnt[dst[e]], 1);
}

__global__ __launch_bounds__(512) void block_reduce(const int* __restrict__ in, int n,
                                                    int* __restrict__ bsum) {
    __shared__ int s[512];
    int i = blockIdx.x * 512 + threadIdx.x;
    s[threadIdx.x] = (i < n) ? in[i] : 0;
    __syncthreads();
    for (int off = 256; off; off >>= 1) {
        if (threadIdx.x < off) s[threadIdx.x] += s[threadIdx.x + off];
        __syncthreads();
    }
    if (threadIdx.x == 0) bsum[blockIdx.x] = s[0];
}

// block 0: exclusive scan of bsum; block 1: graph boundary binary search
__global__ __launch_bounds__(512) void scan_and_bounds(int* bsum, int nb,
                                                       const int* __restrict__ batch, int n,
                                                       int ng, int* __restrict__ gstart) {
    if (blockIdx.x == 1) {
        int b = threadIdx.x;
        if (b == 0) gstart[ng] = n;
        if (b < ng) {
            int lo = 0, hi = n;
            while (lo < hi) {
                int mid = (lo + hi) >> 1;
                if (batch[mid] < b) lo = mid + 1; else hi = mid;
            }
            gstart[b] = lo;
        }
        return;
    }
    __shared__ int buf[2][512];
    int t = threadIdx.x;
    int v = (t < nb) ? bsum[t] : 0;
    buf[0][t] = v;
    __syncthreads();
    int src = 0;
    for (int off = 1; off < 512; off <<= 1) {
        int x = buf[src][t];
        if (t >= off) x += buf[src][t - off];
        buf[src ^ 1][t] = x;
        src ^= 1;
        __syncthreads();
    }
    if (t < nb) bsum[t] = buf[src][t] - v;  // exclusive
}

// also emits dinv[i] = rsqrt(cnt[i]+1)
__global__ __launch_bounds__(512) void block_scan_write(const int* __restrict__ cnt,
                                                        const int* __restrict__ bsum, int n,
                                                        int* __restrict__ rowptr,
                                                        float* __restrict__ dinv) {
    __shared__ int buf[2][512];
    int t = threadIdx.x;
    int i = blockIdx.x * 512 + t;
    int v = (i < n) ? cnt[i] : 0;
    buf[0][t] = v;
    __syncthreads();
    int src = 0;
    for (int off = 1; off < 512; off <<= 1) {
        int x = buf[src][t];
        if (t >= off) x += buf[src][t - off];
        buf[src ^ 1][t] = x;
        src ^= 1;
        __syncthreads();
    }
    int incl = buf[src][t];
    int base = bsum[blockIdx.x];
    if (i < n) {
        rowptr[i] = base + incl - v;
        dinv[i] = rsqrtf((float)(v + 1));
    }
    if (i == n - 1) rowptr[n] = base + incl;
}

__global__ __launch_bounds__(256) void fill_csr(const int* __restrict__ src,
                                                const int* __restrict__ dst, int E,
                                                const int* __restrict__ rowptr,
                                                int* __restrict__ cur, int* __restrict__ col) {
    int e = blockIdx.x * 256 + threadIdx.x;
    if (e < E) {
        int d = dst[e];
        int p = atomicAdd(&cur[d], 1);
        col[rowptr[d] + p] = src[e];
    }
}

// ---- aggregation on pre-scaled features: out[v] = dinv[v]*(sum_{u in N(v)} X[u] + X[v]) ----
// edge loop unrolled x4: four independent gather/accumulate chains for MLP.

template <int LD, int NCH, int NPB>
__global__ __launch_bounds__(256) void agg_sum(const unsigned short* __restrict__ X,
                                               const float* __restrict__ dinv,
                                               const int* __restrict__ rowptr,
                                               const int* __restrict__ col,
                                               unsigned short* __restrict__ out) {
    int tid = threadIdx.x;
    if (tid >= NPB * NCH) return;
    int v = blockIdx.x * NPB + tid / NCH;
    int c = tid % NCH;
    if (v >= N_NODES) return;
    const unsigned short* Xc = X + c * 8;
    u32x4 xv = *(const u32x4*)(Xc + (size_t)v * LD);
    float a0 = bf2f(xv.x & 0xffffu), a1 = bf2f(xv.x >> 16);
    float a2 = bf2f(xv.y & 0xffffu), a3 = bf2f(xv.y >> 16);
    float a4 = bf2f(xv.z & 0xffffu), a5 = bf2f(xv.z >> 16);
    float a6 = bf2f(xv.w & 0xffffu), a7 = bf2f(xv.w >> 16);
    float b0 = 0.f, b1 = 0.f, b2 = 0.f, b3 = 0.f, b4 = 0.f, b5 = 0.f, b6 = 0.f, b7 = 0.f;
    float c0 = 0.f, c1 = 0.f, c2 = 0.f, c3 = 0.f, c4 = 0.f, c5 = 0.f, c6 = 0.f, c7 = 0.f;
    float d0 = 0.f, d1 = 0.f, d2 = 0.f, d3 = 0.f, d4 = 0.f, d5 = 0.f, d6 = 0.f, d7 = 0.f;
    int r0 = rowptr[v], r1 = rowptr[v + 1];
    int e = r0;
    for (; e + 3 < r1; e += 4) {
        int u0 = col[e], u1 = col[e + 1], u2 = col[e + 2], u3 = col[e + 3];
        u32x4 p = *(const u32x4*)(Xc + (size_t)u0 * LD);
        u32x4 q = *(const u32x4*)(Xc + (size_t)u1 * LD);
        u32x4 s = *(const u32x4*)(Xc + (size_t)u2 * LD);
        u32x4 t = *(const u32x4*)(Xc + (size_t)u3 * LD);
        a0 += bf2f(p.x & 0xffffu); a1 += bf2f(p.x >> 16);
        a2 += bf2f(p.y & 0xffffu); a3 += bf2f(p.y >> 16);
        a4 += bf2f(p.z & 0xffffu); a5 += bf2f(p.z >> 16);
        a6 += bf2f(p.w & 0xffffu); a7 += bf2f(p.w >> 16);
        b0 += bf2f(q.x & 0xffffu); b1 += bf2f(q.x >> 16);
        b2 += bf2f(q.y & 0xffffu); b3 += bf2f(q.y >> 16);
        b4 += bf2f(q.z & 0xffffu); b5 += bf2f(q.z >> 16);
        b6 += bf2f(q.w & 0xffffu); b7 += bf2f(q.w >> 16);
        c0 += bf2f(s.x & 0xffffu); c1 += bf2f(s.x >> 16);
        c2 += bf2f(s.y & 0xffffu); c3 += bf2f(s.y >> 16);
        c4 += bf2f(s.z & 0xffffu); c5 += bf2f(s.z >> 16);
        c6 += bf2f(s.w & 0xffffu); c7 += bf2f(s.w >> 16);
        d0 += bf2f(t.x & 0xffffu); d1 += bf2f(t.x >> 16);
        d2 += bf2f(t.y & 0xffffu); d3 += bf2f(t.y >> 16);
        d4 += bf2f(t.z & 0xffffu); d5 += bf2f(t.z >> 16);
        d6 += bf2f(t.w & 0xffffu); d7 += bf2f(t.w >> 16);
    }
    for (; e < r1; ++e) {
        int u = col[e];
        u32x4 p = *(const u32x4*)(Xc + (size_t)u * LD);
        a0 += bf2f(p.x & 0xffffu); a1 += bf2f(p.x >> 16);
        a2 += bf2f(p.y & 0xffffu); a3 += bf2f(p.y >> 16);
        a4 += bf2f(p.z & 0xffffu); a5 += bf2f(p.z >> 16);
        a6 += bf2f(p.w & 0xffffu); a7 += bf2f(p.w >> 16);
    }
    float dv = dinv[v];
    u32x4 o;
    o.x = ((unsigned int)f2bf((a1 + b1 + c1 + d1) * dv) << 16) | f2bf((a0 + b0 + c0 + d0) * dv);
    o.y = ((unsigned int)f2bf((a3 + b3 + c3 + d3) * dv) << 16) | f2bf((a2 + b2 + c2 + d2) * dv);
    o.z = ((unsigned int)f2bf((a5 + b5 + c5 + d5) * dv) << 16) | f2bf((a4 + b4 + c4 + d4) * dv);
    o.w = ((unsigned int)f2bf((a7 + b7 + c7 + d7) * dv) << 16) | f2bf((a6 + b6 + c6 + d6) * dv);
    *(u32x4*)(out + (size_t)v * LD + c * 8) = o;
}

// ---- merged one-time setup: scale_x + all fragment-ordered bf16 weight conversions ----

__device__ inline void prep_wf_body(const float* __restrict__ W, unsigned short* __restrict__ Wf,
                                    int idx, int KREAL, int NREAL, int KS, int NF) {
    if (idx >= NF * KS * 64) return;
    int lane = idx & 63, ks = (idx >> 6) % KS, nf = idx / (64 * KS);
    int k0 = ks * 32 + 8 * (lane >> 4);
    int cc = nf * 16 + (lane & 15);
    short8v t;
#pragma unroll
    for (int j = 0; j < 8; j++) {
        int k = k0 + j;
        float w = (k < KREAL && cc < NREAL) ? W[(size_t)k * NREAL + cc] : 0.f;
        t[j] = (short)f2bf(w);
    }
    *(short8v*)&Wf[(size_t)idx * 8] = t;
}

#define SETUP_SCALE_BLOCKS 31250  // N*40/256
#define SETUP_BLOCKS (SETUP_SCALE_BLOCKS + 128 + 14 + 4 + 8 + 25 + 160 + 64 + 242 + 128 + 256)

__global__ __launch_bounds__(256) void setup_misc(
    const float* __restrict__ x, const float* __restrict__ dinv, unsigned short* __restrict__ XS,
    const float* __restrict__ convw, unsigned short* __restrict__ CWf,
    const float* __restrict__ emb, unsigned short* __restrict__ Ef,
    const float* __restrict__ W1, unsigned short* __restrict__ W1f,
    const float* __restrict__ W2, unsigned short* __restrict__ W2f,
    const float* __restrict__ W3, unsigned short* __restrict__ W3f,
    const float* __restrict__ Wg1, unsigned short* __restrict__ Wg1f,
    const float* __restrict__ Wg2, unsigned short* __restrict__ Wg2f,
    const float* __restrict__ Wxt, unsigned short* __restrict__ Wxtf,
    const float* __restrict__ Wf1, unsigned short* __restrict__ Wf1f,
    const float* __restrict__ Wf2, unsigned short* __restrict__ Wf2f) {
    int b = blockIdx.x;
    int tid = threadIdx.x;
    if (b < SETUP_SCALE_BLOCKS) {  // scale_x: xs[v] = x[v]*dinv[v] -> bf16 [N][80]
        int idx = b * 256 + tid;
        int v = idx / 40, c = idx % 40;
        if (v >= N_NODES) return;
        if (c == 39) {
            *(unsigned int*)(XS + (size_t)v * 80 + 78) = 0u;
            return;
        }
        float dv = dinv[v];
        f32x2 xv = *(const f32x2*)(x + (size_t)v * 78 + c * 2);
        unsigned int pack = ((unsigned int)f2bf(xv.y * dv) << 16) | f2bf(xv.x * dv);
        *(unsigned int*)(XS + (size_t)v * 80 + c * 2) = pack;
        return;
    }
    b -= SETUP_SCALE_BLOCKS;
    if (b < 128) {  // prep_cwf
        int idx = b * 256 + tid;
        int ks = idx >> 10, nf = (idx >> 6) & 15, lane = idx & 63;
        int k0 = ks * 32 + 8 * (lane >> 4);
        int c = nf * 16 + (lane & 15);
        int o = c >> 3, kk = c & 7;
        short8v t;
#pragma unroll
        for (int j = 0; j < 8; j++) {
            int k = k0 + j;
            float v = (k < 1000) ? convw[(size_t)o * 8000 + k * 8 + kk] : 0.f;
            t[j] = (short)f2bf(v);
        }
        *(short8v*)&CWf[(size_t)idx * 8] = t;
        return;
    }
    b -= 128;
    if (b < 14) {  // prep_ef
        int idx = b * 256 + tid;
        if (idx >= 7 * 8 * 64) return;
        int ks = idx >> 9, nf = (idx >> 6) & 7, lane = idx & 63;
        int j0 = ks * 32 + 8 * (lane >> 4);
        int w = nf * 16 + (lane & 15);
        short8v t;
#pragma unroll
        for (int j8 = 0; j8 < 8; j8++) {
            int j = j0 + j8;
            float v = (j < 208 && w < 121) ? emb[(size_t)(j >> 3) * 128 + w + (j & 7)] : 0.f;
            t[j8] = (short)f2bf(v);
        }
        *(short8v*)&Ef[(size_t)idx * 8] = t;
        return;
    }
    b -= 14;
    if (b < 4) { prep_wf_body(W1, W1f, b * 256 + tid, 78, 78, 3, 5); return; }
    b -= 4;
    if (b < 8) { prep_wf_body(W2, W2f, b * 256 + tid, 78, 156, 3, 10); return; }
    b -= 8;
    if (b < 25) { prep_wf_body(W3, W3f, b * 256 + tid, 156, 312, 5, 20); return; }
    b -= 25;
    if (b < 160) { prep_wf_body(Wg1, Wg1f, b * 256 + tid, 312, 1024, 10, 64); return; }
    b -= 160;
    if (b < 64) { prep_wf_body(Wg2, Wg2f, b * 256 + tid, 1024, 128, 32, 8); return; }
    b -= 64;
    if (b < 242) { prep_wf_body(Wxt, Wxtf, b * 256 + tid, 3872, 128, 121, 8); return; }
    b -= 242;
    if (b < 128) { prep_wf_body(Wf1, Wf1f, b * 256 + tid, 256, 1024, 8, 64); return; }
    b -= 128;
    prep_wf_body(Wf2, Wf2f, b * 256 + tid, 1024, 512, 32, 32);
}

// ------- MFMA node GEMM: Cout = relu(A @ W + bias) * dinv[row], bf16 in/out -------

template <int NREAL, int LDA, int LDC, int NF, int KS>
__global__ __launch_bounds__(256) void gemm_mfma_node(const unsigned short* __restrict__ A,
                                                      const unsigned short* __restrict__ Wf,
                                                      const float* __restrict__ bias,
                                                      const float* __restrict__ dinv,
                                                      unsigned short* __restrict__ Cout, int M) {
    __shared__ unsigned short Bs[NF * KS * 64 * 8];
    int tid = threadIdx.x;
    for (int idx = tid; idx < NF * KS * 64; idx += 256)
        *(short8v*)&Bs[idx * 8] = *(const short8v*)&Wf[(size_t)idx * 8];
    __syncthreads();

    int lane = tid & 63, wid = tid >> 6;
    int m0 = blockIdx.x * 128 + wid * 32;
    float biasr[NF];
#pragma unroll
    for (int nf = 0; nf < NF; nf++) {
        int cc = nf * 16 + (lane & 15);
        biasr[nf] = (cc < NREAL) ? bias[cc] : 0.f;
    }
    f32x4 acc[2][NF];
#pragma unroll
    for (int mf = 0; mf < 2; mf++)
#pragma unroll
        for (int nf = 0; nf < NF; nf++) acc[mf][nf] = (f32x4){0.f, 0.f, 0.f, 0.f};

    int ra = min(m0 + (lane & 15), M - 1);
    int rb = min(m0 + 16 + (lane & 15), M - 1);
#pragma unroll
    for (int ks = 0; ks < KS; ks++) {
        int koff = ks * 32 + 8 * (lane >> 4);
        short8v a0 = *(const short8v*)(A + (size_t)ra * LDA + koff);
        short8v a1 = *(const short8v*)(A + (size_t)rb * LDA + koff);
#pragma unroll
        for (int nf = 0; nf < NF; nf++) {
            short8v b = *(const short8v*)&Bs[((nf * KS + ks) * 64 + lane) * 8];
            acc[0][nf] = __builtin_amdgcn_mfma_f32_16x16x32_bf16(a0, b, acc[0][nf], 0, 0, 0);
            acc[1][nf] = __builtin_amdgcn_mfma_f32_16x16x32_bf16(a1, b, acc[1][nf], 0, 0, 0);
        }
    }
    float dr[2][4];
#pragma unroll
    for (int mf = 0; mf < 2; mf++)
#pragma unroll
        for (int r = 0; r < 4; r++) {
            int row = m0 + mf * 16 + 4 * (lane >> 4) + r;
            dr[mf][r] = dinv[min(row, M - 1)];
        }
#pragma unroll
    for (int mf = 0; mf < 2; mf++) {
#pragma unroll
        for (int nf = 0; nf < NF; nf++) {
            int cc = nf * 16 + (lane & 15);
#pragma unroll
            for (int r = 0; r < 4; r++) {
                int row = m0 + mf * 16 + 4 * (lane >> 4) + r;
                float v = fmaxf(acc[mf][nf][r] + biasr[nf], 0.f) * dr[mf][r];
                unsigned short o = (cc < NREAL) ? f2bf(v) : (unsigned short)0;
                if (row < M) Cout[(size_t)row * LDC + cc] = o;
            }
        }
    }
}

// ------- layer-3 GEMM fused with per-graph segment-max ----
// 1D grid 2560: bx = id>>9 (col-block of 64), g = id&511 (graph). All 5 col-blocks of a
// graph share XCD (512 % 8 == 0) -> A rows L2-hit after first touch.

__global__ __launch_bounds__(256) void seg_gemm_max(const unsigned short* __restrict__ A,
                                                    const unsigned short* __restrict__ Wf3,
                                                    const float* __restrict__ b3,
                                                    const int* __restrict__ gstart,
                                                    float* __restrict__ g3) {
    __shared__ unsigned short Bs[4 * 5 * 64 * 8];  // 20 KB
    __shared__ float wmax[4][64];
    int g = blockIdx.x & 511;
    int bx = blockIdx.x >> 9;
    int c0 = bx * 64;
    int r0 = gstart[g], r1 = gstart[g + 1];
    int tid = threadIdx.x, lane = tid & 63, wid = tid >> 6;

    const unsigned short* src = Wf3 + (size_t)bx * 4 * 5 * 64 * 8;
    for (int idx = tid; idx < 1280; idx += 256)
        *(short8v*)&Bs[idx * 8] = *(const short8v*)&src[(size_t)idx * 8];
    __syncthreads();

    float biasr[4], cmax[4];
#pragma unroll
    for (int nf = 0; nf < 4; nf++) {
        int cc = c0 + nf * 16 + (lane & 15);
        biasr[nf] = (cc < 312) ? b3[cc] : 0.f;
        cmax[nf] = 0.f;
    }

    for (int mt = r0 + wid * 32; mt < r1; mt += 128) {
        f32x4 acc[2][4];
#pragma unroll
        for (int mf = 0; mf < 2; mf++)
#pragma unroll
            for (int nf = 0; nf < 4; nf++) acc[mf][nf] = (f32x4){0.f, 0.f, 0.f, 0.f};
        int ra = min(mt + (lane & 15), N_NODES - 1);
        int rb = min(mt + 16 + (lane & 15), N_NODES - 1);
#pragma unroll
        for (int ks = 0; ks < 5; ks++) {
            int koff = ks * 32 + 8 * (lane >> 4);
            short8v a0 = *(const short8v*)(A + (size_t)ra * 160 + koff);
            short8v a1 = *(const short8v*)(A + (size_t)rb * 160 + koff);
#pragma unroll
            for (int nf = 0; nf < 4; nf++) {
                short8v b = *(const short8v*)&Bs[((nf * 5 + ks) * 64 + lane) * 8];
                acc[0][nf] = __builtin_amdgcn_mfma_f32_16x16x32_bf16(a0, b, acc[0][nf], 0, 0, 0);
                acc[1][nf] = __builtin_amdgcn_mfma_f32_16x16x32_bf16(a1, b, acc[1][nf], 0, 0, 0);
            }
        }
#pragma unroll
        for (int mf = 0; mf < 2; mf++) {
#pragma unroll
            for (int nf = 0; nf < 4; nf++) {
#pragma unroll
                for (int r = 0; r < 4; r++) {
                    int row = mt + mf * 16 + 4 * (lane >> 4) + r;
                    float v = fmaxf(acc[mf][nf][r] + biasr[nf], 0.f);
                    if (row < r1) cmax[nf] = fmaxf(cmax[nf], v);
                }
            }
        }
    }
#pragma unroll
    for (int nf = 0; nf < 4; nf++) {
        float m = cmax[nf];
        m = fmaxf(m, __shfl_xor(m, 16));
        m = fmaxf(m, __shfl_xor(m, 32));
        if (lane < 16) wmax[wid][nf * 16 + lane] = m;
    }
    __syncthreads();
    if (tid < 64) {
        float m = fmaxf(fmaxf(wmax[0][tid], wmax[1][tid]), fmaxf(wmax[2][tid], wmax[3][tid]));
        int cc = c0 + tid;
        if (cc < 312) g3[(size_t)g * 312 + cc] = m;
    }
}

// ---------------- head GEMMs: single-pass MFMA, no LDS, no atomics ----------------
// C[512, N] = act(A[512, K] @ W + bias). A f32 (rows contiguous, stride K), W pre-converted
// fragment bf16. Grid (N/64, 4). Wave owns 32 rows x 64 cols. K padded by zero frags.

template <int ACT, int KS, int K, int LDC, int COFF>
__global__ __launch_bounds__(256) void head_mfma(const float* __restrict__ A,
                                                 const unsigned short* __restrict__ Wf,
                                                 const float* __restrict__ bias,
                                                 float* __restrict__ C) {
    int tid = threadIdx.x, lane = tid & 63, wid = tid >> 6;
    int hi = lane >> 4, l15 = lane & 15;
    int m0 = blockIdx.y * 128 + wid * 32;
    int n0 = blockIdx.x * 64;
    f32x4 acc[2][4];
#pragma unroll
    for (int mf = 0; mf < 2; mf++)
#pragma unroll
        for (int nf = 0; nf < 4; nf++) acc[mf][nf] = (f32x4){0.f, 0.f, 0.f, 0.f};
    const float* Ar0 = A + (size_t)(m0 + l15) * K;
    const float* Ar1 = A + (size_t)(m0 + 16 + l15) * K;
#pragma unroll 2
    for (int ks = 0; ks < KS; ks++) {
        int k0 = ks * 32 + 8 * hi;
        f32x4 p0 = *(const f32x4*)(Ar0 + k0);
        f32x4 p1 = *(const f32x4*)(Ar0 + k0 + 4);
        f32x4 q0 = *(const f32x4*)(Ar1 + k0);
        f32x4 q1 = *(const f32x4*)(Ar1 + k0 + 4);
        short8v a0, a1;
        a0[0] = (short)f2bf(p0.x); a0[1] = (short)f2bf(p0.y);
        a0[2] = (short)f2bf(p0.z); a0[3] = (short)f2bf(p0.w);
        a0[4] = (short)f2bf(p1.x); a0[5] = (short)f2bf(p1.y);
        a0[6] = (short)f2bf(p1.z); a0[7] = (short)f2bf(p1.w);
        a1[0] = (short)f2bf(q0.x); a1[1] = (short)f2bf(q0.y);
        a1[2] = (short)f2bf(q0.z); a1[3] = (short)f2bf(q0.w);
        a1[4] = (short)f2bf(q1.x); a1[5] = (short)f2bf(q1.y);
        a1[6] = (short)f2bf(q1.z); a1[7] = (short)f2bf(q1.w);
#pragma unroll
        for (int nf = 0; nf < 4; nf++) {
            int nfg = blockIdx.x * 4 + nf;
            short8v b = *(const short8v*)&Wf[((size_t)(nfg * KS + ks) * 64 + lane) * 8];
            acc[0][nf] = __builtin_amdgcn_mfma_f32_16x16x32_bf16(a0, b, acc[0][nf], 0, 0, 0);
            acc[1][nf] = __builtin_amdgcn_mfma_f32_16x16x32_bf16(a1, b, acc[1][nf], 0, 0, 0);
        }
    }
#pragma unroll
    for (int mf = 0; mf < 2; mf++) {
#pragma unroll
        for (int nf = 0; nf < 4; nf++) {
            int cc = n0 + nf * 16 + l15;
            float bj = bias[cc];
#pragma unroll
            for (int r = 0; r < 4; r++) {
                int row = m0 + mf * 16 + 4 * hi + r;
                float v = acc[mf][nf][r] + bj;
                if (ACT) v = fmaxf(v, 0.f);
                C[(size_t)row * LDC + COFF + cc] = v;
            }
        }
    }
}

// Wxt split-K stage 1: cpart[kz][512][128], kz = 11 chunks of 11 frags (121 = 11*11)
__global__ __launch_bounds__(256) void head_mfma_part(const float* __restrict__ A,
                                                      const unsigned short* __restrict__ Wf,
                                                      float* __restrict__ cpart) {
    int tid = threadIdx.x, lane = tid & 63, wid = tid >> 6;
    int hi = lane >> 4, l15 = lane & 15;
    int m0 = blockIdx.y * 128 + wid * 32;
    int n0 = blockIdx.x * 64;
    int kz = blockIdx.z;
    f32x4 acc[2][4];
#pragma unroll
    for (int mf = 0; mf < 2; mf++)
#pragma unroll
        for (int nf = 0; nf < 4; nf++) acc[mf][nf] = (f32x4){0.f, 0.f, 0.f, 0.f};
    const float* Ar0 = A + (size_t)(m0 + l15) * 3872;
    const float* Ar1 = A + (size_t)(m0 + 16 + l15) * 3872;
    for (int i = 0; i < 11; i++) {
        int ks = kz * 11 + i;
        int k0 = ks * 32 + 8 * hi;
        f32x4 p0 = *(const f32x4*)(Ar0 + k0);
        f32x4 p1 = *(const f32x4*)(Ar0 + k0 + 4);
        f32x4 q0 = *(const f32x4*)(Ar1 + k0);
        f32x4 q1 = *(const f32x4*)(Ar1 + k0 + 4);
        short8v a0, a1;
        a0[0] = (short)f2bf(p0.x); a0[1] = (short)f2bf(p0.y);
        a0[2] = (short)f2bf(p0.z); a0[3] = (short)f2bf(p0.w);
        a0[4] = (short)f2bf(p1.x); a0[5] = (short)f2bf(p1.y);
        a0[6] = (short)f2bf(p1.z); a0[7] = (short)f2bf(p1.w);
        a1[0] = (short)f2bf(q0.x); a1[1] = (short)f2bf(q0.y);
        a1[2] = (short)f2bf(q0.z); a1[3] = (short)f2bf(q0.w);
        a1[4] = (short)f2bf(q1.x); a1[5] = (short)f2bf(q1.y);
        a1[6] = (short)f2bf(q1.z); a1[7] = (short)f2bf(q1.w);
#pragma unroll
        for (int nf = 0; nf < 4; nf++) {
            int nfg = blockIdx.x * 4 + nf;
            short8v b = *(const short8v*)&Wf[((size_t)(nfg * 121 + ks) * 64 + lane) * 8];
            acc[0][nf] = __builtin_amdgcn_mfma_f32_16x16x32_bf16(a0, b, acc[0][nf], 0, 0, 0);
            acc[1][nf] = __builtin_amdgcn_mfma_f32_16x16x32_bf16(a1, b, acc[1][nf], 0, 0, 0);
        }
    }
#pragma unroll
    for (int mf = 0; mf < 2; mf++) {
#pragma unroll
        for (int nf = 0; nf < 4; nf++) {
            int cc = n0 + nf * 16 + l15;
#pragma unroll
            for (int r = 0; r < 4; r++) {
                int row = m0 + mf * 16 + 4 * hi + r;
                cpart[((size_t)kz * 512 + row) * 128 + cc] = acc[mf][nf][r];
            }
        }
    }
}

// Wxt split-K stage 2: xc[:,128:] = sum_kz cpart + bxt
__global__ __launch_bounds__(256) void reduce_xt(const float* __restrict__ cpart,
                                                 const float* __restrict__ bxt,
                                                 float* __restrict__ xc) {
    int idx = blockIdx.x * 256 + threadIdx.x;
    if (idx >= 512 * 128) return;
    int row = idx >> 7, c = idx & 127;
    float s = bxt[c];
#pragma unroll
    for (int k = 0; k < 11; k++) s += cpart[((size_t)k * 512 + row) * 128 + c];
    xc[(size_t)row * 256 + 128 + c] = s;
}

// ---------------- conv head via MFMA ----------------

__global__ __launch_bounds__(256) void conv_mfma(const int* __restrict__ target,
                                                 const unsigned short* __restrict__ CWf,
                                                 const unsigned short* __restrict__ Ef,
                                                 const float* __restrict__ convb,
                                                 float* __restrict__ c) {
    __shared__ int tg[1024];
    __shared__ unsigned short A_lds[32 * 256];  // 16 KB
    int n = blockIdx.x;
    int tid = threadIdx.x, lane = tid & 63, wid = tid >> 6;
    int hi = lane >> 4, l15 = lane & 15;
    for (int i = tid; i < 1024; i += 256) tg[i] = (i < 1000) ? target[n * 1000 + i] : -1;
    __syncthreads();

    // phase A: A = onehot @ CW; wave owns 4 of 16 col-frags
    f32x4 acc[2][4];
#pragma unroll
    for (int mf = 0; mf < 2; mf++)
#pragma unroll
        for (int nf = 0; nf < 4; nf++) acc[mf][nf] = (f32x4){0.f, 0.f, 0.f, 0.f};
    int r0 = l15, r1 = l15 + 16;
    for (int ks = 0; ks < 32; ks++) {
        int kk = ks * 32 + 8 * hi;
        i32x4 ta = *(const i32x4*)&tg[kk];
        i32x4 tb = *(const i32x4*)&tg[kk + 4];
        short8v a0, a1;
        a0[0] = (ta.x == r0) ? (short)0x3F80 : (short)0;
        a0[1] = (ta.y == r0) ? (short)0x3F80 : (short)0;
        a0[2] = (ta.z == r0) ? (short)0x3F80 : (short)0;
        a0[3] = (ta.w == r0) ? (short)0x3F80 : (short)0;
        a0[4] = (tb.x == r0) ? (short)0x3F80 : (short)0;
        a0[5] = (tb.y == r0) ? (short)0x3F80 : (short)0;
        a0[6] = (tb.z == r0) ? (short)0x3F80 : (short)0;
        a0[7] = (tb.w == r0) ? (short)0x3F80 : (short)0;
        a1[0] = (ta.x == r1) ? (short)0x3F80 : (short)0;
        a1[1] = (ta.y == r1) ? (short)0x3F80 : (short)0;
        a1[2] = (ta.z == r1) ? (short)0x3F80 : (short)0;
        a1[3] = (ta.w == r1) ? (short)0x3F80 : (short)0;
        a1[4] = (tb.x == r1) ? (short)0x3F80 : (short)0;
        a1[5] = (tb.y == r1) ? (short)0x3F80 : (short)0;
        a1[6] = (tb.z == r1) ? (short)0x3F80 : (short)0;
        a1[7] = (tb.w == r1) ? (short)0x3F80 : (short)0;
#pragma unroll
        for (int nf = 0; nf < 4; nf++) {
            short8v b = *(const short8v*)&CWf[((size_t)(ks * 16 + wid * 4 + nf) * 64 + lane) * 8];
            acc[0][nf] = __builtin_amdgcn_mfma_f32_16x16x32_bf16(a0, b, acc[0][nf], 0, 0, 0);
            acc[1][nf] = __builtin_amdgcn_mfma_f32_16x16x32_bf16(a1, b, acc[1][nf], 0, 0, 0);
        }
    }
#pragma unroll
    for (int mf = 0; mf < 2; mf++)
#pragma unroll
        for (int nf = 0; nf < 4; nf++) {
            int col = (wid * 4 + nf) * 16 + l15;
#pragma unroll
            for (int r = 0; r < 4; r++) {
                int row = 16 * mf + 4 * hi + r;
                A_lds[row * 256 + col] = f2bf(acc[mf][nf][r]);
            }
        }
    __syncthreads();

    // phase B: c = A'' @ E; wave owns 2 of 8 col-frags (w range)
    f32x4 acc2[2][2];
#pragma unroll
    for (int mf = 0; mf < 2; mf++)
#pragma unroll
        for (int nf = 0; nf < 2; nf++) acc2[mf][nf] = (f32x4){0.f, 0.f, 0.f, 0.f};
#pragma unroll
    for (int ks = 0; ks < 7; ks++) {
        int j0 = ks * 32 + 8 * hi;
        int t = j0 >> 3;
        short8v a0 = *(const short8v*)&A_lds[t * 256 + l15 * 8];
        short8v a1 = *(const short8v*)&A_lds[t * 256 + (l15 + 16) * 8];
#pragma unroll
        for (int nf = 0; nf < 2; nf++) {
            short8v b = *(const short8v*)&Ef[((size_t)(ks * 8 + wid * 2 + nf) * 64 + lane) * 8];
            acc2[0][nf] = __builtin_amdgcn_mfma_f32_16x16x32_bf16(a0, b, acc2[0][nf], 0, 0, 0);
            acc2[1][nf] = __builtin_amdgcn_mfma_f32_16x16x32_bf16(a1, b, acc2[1][nf], 0, 0, 0);
        }
    }
#pragma unroll
    for (int mf = 0; mf < 2; mf++)
#pragma unroll
        for (int nf = 0; nf < 2; nf++) {
            int w = (wid * 2 + nf) * 16 + l15;
            if (w < 121) {
#pragma unroll
                for (int r = 0; r < 4; r++) {
                    int o = 16 * mf + 4 * hi + r;
                    c[(size_t)n * 3872 + o * 121 + w] = acc2[mf][nf][r] + convb[o];
                }
            }
        }
}

// ---------------- final N=1 matvec (f2 already post-relu) ----------------

__global__ __launch_bounds__(256) void rowdot(const float* __restrict__ f2,
                                              const float* __restrict__ Wo,
                                              const float* __restrict__ bo,
                                              float* __restrict__ out, int M, int K) {
    int row = blockIdx.x * 4 + (threadIdx.x >> 6);
    int lane = threadIdx.x & 63;
    if (row >= M) return;
    float acc = 0.f;
    for (int k = lane; k < K; k += 64) acc += f2[(size_t)row * K + k] * Wo[k];
    for (int off = 32; off; off >>= 1) acc += __shfl_down(acc, off);
    if (lane == 0) out[row] = acc + bo[0];
}

// ---------------- launch ----------------

extern "C" void kernel_launch(void* const* d_in, const int* in_sizes, int n_in, void* d_out,
                              int out_size, void* d_ws, size_t ws_size, hipStream_t stream) {
    const float* x = (const float*)d_in[0];
    const int* ei = (const int*)d_in[1];
    const int* batch = (const int*)d_in[2];
    const int* target = (const int*)d_in[3];
    const float* W1 = (const float*)d_in[4];
    const float* b1 = (const float*)d_in[5];
    const float* W2 = (const float*)d_in[6];
    const float* b2 = (const float*)d_in[7];
    const float* W3 = (const float*)d_in[8];
    const float* b3 = (const float*)d_in[9];
    const float* Wg1 = (const float*)d_in[10];
    const float* bg1 = (const float*)d_in[11];
    const float* Wg2 = (const float*)d_in[12];
    const float* bg2 = (const float*)d_in[13];
    const float* emb = (const float*)d_in[14];
    const float* convw = (const float*)d_in[15];
    const float* convb = (const float*)d_in[16];
    const float* Wxt = (const float*)d_in[17];
    const float* bxt = (const float*)d_in[18];
    const float* Wf1 = (const float*)d_in[19];
    const float* bf1 = (const float*)d_in[20];
    const float* Wf2 = (const float*)d_in[21];
    const float* bf2 = (const float*)d_in[22];
    const float* Wo = (const float*)d_in[23];
    const float* bo = (const float*)d_in[24];
    float* out = (float*)d_out;

    const int N = N_NODES, E = N_EDGES;
    const int NB = (N + 511) / 512;

    char* ws = (char*)d_ws;
    size_t off = 0;
    auto alloc = [&](size_t bytes) -> char* {
        char* p = ws + off;
        off = (off + bytes + 255) & ~(size_t)255;
        return p;
    };
    int* cnt = (int*)alloc((size_t)N * 2 * 4);  // cnt + cur, one memset
    int* cur = cnt + N;
    int* rowptr = (int*)alloc((size_t)(N + 1) * 4);
    int* bsum = (int*)alloc(512 * 4);
    int* col = (int*)alloc((size_t)E * 4);
    float* dinv = (float*)alloc((size_t)N * 4);
    int* gstart = (int*)alloc((N_GRAPHS + 1) * 4);
    float* g3 = (float*)alloc((size_t)N_GRAPHS * 312 * 4);
    float* gg = (float*)alloc((size_t)N_GRAPHS * 1024 * 4);
    float* cbuf = (float*)alloc((size_t)N_GRAPHS * 3872 * 4);
    float* xc = (float*)alloc((size_t)N_GRAPHS * 256 * 4);
    float* f1 = (float*)alloc((size_t)N_GRAPHS * 1024 * 4);
    float* f2 = (float*)alloc((size_t)N_GRAPHS * 512 * 4);
    float* cpart = (float*)alloc((size_t)11 * 512 * 128 * 4);  // 2.9 MB
    unsigned short* CWf = (unsigned short*)alloc((size_t)32768 * 8 * 2);  // 512 KB
    unsigned short* Ef = (unsigned short*)alloc((size_t)3584 * 8 * 2);    // 56 KB
    unsigned short* W1f = (unsigned short*)alloc((size_t)5 * 3 * 64 * 8 * 2);
    unsigned short* W2f = (unsigned short*)alloc((size_t)10 * 3 * 64 * 8 * 2);
    unsigned short* W3f = (unsigned short*)alloc((size_t)20 * 5 * 64 * 8 * 2);
    unsigned short* Wg1f = (unsigned short*)alloc((size_t)64 * 10 * 64 * 8 * 2);
    unsigned short* Wg2f = (unsigned short*)alloc((size_t)8 * 32 * 64 * 8 * 2);
    unsigned short* Wxtf = (unsigned short*)alloc((size_t)8 * 121 * 64 * 8 * 2);
    unsigned short* Wf1f = (unsigned short*)alloc((size_t)64 * 8 * 64 * 8 * 2);
    unsigned short* Wf2f = (unsigned short*)alloc((size_t)32 * 32 * 64 * 8 * 2);
    unsigned short* U = (unsigned short*)alloc((size_t)N * 160 * 2 + 512);
    unsigned short* P160 = (unsigned short*)alloc((size_t)N * 160 * 2 + 512);
    unsigned short* H1 = U + (size_t)N * 80;  // [N,80] second half of U

    const int* srcp = ei;
    const int* dstp = ei + E;

    // CSR + norm (+ graph bounds + dinv folded in)
    hipMemsetAsync(cnt, 0, (size_t)N * 2 * 4, stream);
    count_edges<<<(E + 255) / 256, 256, 0, stream>>>(dstp, E, cnt);
    block_reduce<<<NB, 512, 0, stream>>>(cnt, N, bsum);
    scan_and_bounds<<<2, 512, 0, stream>>>(bsum, NB, batch, N, N_GRAPHS, gstart);
    block_scan_write<<<NB, 512, 0, stream>>>(cnt, bsum, N, rowptr, dinv);
    fill_csr<<<(E + 255) / 256, 256, 0, stream>>>(srcp, dstp, E, rowptr, cur, col);

    // merged one-time setup: scale_x + all operand preps
    setup_misc<<<SETUP_BLOCKS, 256, 0, stream>>>(x, dinv, P160, convw, CWf, emb, Ef, W1, W1f, W2,
                                                 W2f, W3, W3f, Wg1, Wg1f, Wg2, Wg2f, Wxt, Wxtf,
                                                 Wf1, Wf1f, Wf2, Wf2f);

    const int MB = (N + 127) / 128;  // 1563

    // layer 1: A1 = aggsum(XS) (U80); h1' = relu(A1@W1+b1)*dinv (H1)
    agg_sum<80, 10, 25><<<(N + 24) / 25, 256, 0, stream>>>(P160, dinv, rowptr, col, U);
    gemm_mfma_node<78, 80, 80, 5, 3><<<MB, 256, 0, stream>>>(U, W1f, b1, dinv, H1, N);
    // layer 2: A2 = aggsum(h1') (P160[:,:80]); h2' = relu(A2@W2+b2)*dinv (U as [N,160])
    agg_sum<80, 10, 25><<<(N + 24) / 25, 256, 0, stream>>>(H1, dinv, rowptr, col, P160);
    gemm_mfma_node<156, 80, 160, 10, 3><<<MB, 256, 0, stream>>>(P160, W2f, b2, dinv, U, N);
    // layer 3: A3 = aggsum(h2') (P160 [N,160]); fused GEMM + per-graph segment max
    agg_sum<160, 20, 12><<<(N + 11) / 12, 256, 0, stream>>>(U, dinv, rowptr, col, P160);
    seg_gemm_max<<<5 * N_GRAPHS, 256, 0, stream>>>(P160, W3f, b3, gstart, g3);

    // graph head: gg = relu(g3@Wg1+bg1); xc[:,:128] = gg@Wg2+bg2
    head_mfma<1, 10, 312, 1024, 0><<<dim3(16, 4), 256, 0, stream>>>(g3, Wg1f, bg1, gg);
    head_mfma<0, 32, 1024, 256, 0><<<dim3(2, 4), 256, 0, stream>>>(gg, Wg2f, bg2, xc);

    // conv head (MFMA) + Wxt split-K
    conv_mfma<<<N_GRAPHS, 256, 0, stream>>>(target, CWf, Ef, convb, cbuf);
    head_mfma_part<<<dim3(2, 4, 11), 256, 0, stream>>>(cbuf, Wxtf, cpart);
    reduce_xt<<<256, 256, 0, stream>>>(cpart, bxt, xc);

    // final MLP: f1 = relu(xc@Wf1+bf1); f2 = relu(f1@Wf2+bf2); out = f2@Wo+bo
    head_mfma<1, 8, 256, 1024, 0><<<dim3(16, 4), 256, 0, stream>>>(xc, Wf1f, bf1, f1);
    head_mfma<1, 32, 1024, 512, 0><<<dim3(8, 4), 256, 0, stream>>>(f1, Wf2f, bf2, f2);
    rowdot<<<(N_GRAPHS + 3) / 4, 256, 0, stream>>>(f2, Wo, bo, out, N_GRAPHS, 512);
}